// Round 7
// baseline (1393.974 us; speedup 1.0000x reference)
//
#include <hip/hip_runtime.h>
#include <hip/hip_bf16.h>
#include <hip/hip_cooperative_groups.h>
#include <math.h>

namespace cg = cooperative_groups;

#define NN 1024
#define BB 4
#define HH 8
#define DD 256
#define LL 4
#define DKK 32
#define MM 4096
#define EPSF 1e-6f

typedef __attribute__((ext_vector_type(8))) short short8;
typedef __attribute__((ext_vector_type(4))) float f32x4;

__device__ __forceinline__ unsigned short f2bf(float f) {
    __hip_bfloat16 h = __float2bfloat16(f);
    return *(unsigned short*)&h;
}
__device__ __forceinline__ float bf2f(unsigned short u) {
    unsigned v = ((unsigned)u) << 16;
    return __builtin_bit_cast(float, v);
}

struct MegaP {
    const float* x; const int* deg_in; const int* deg_out; const int* sp;
    const float* svd; const float* in_emb; const float* out_emb; const float* spemb;
    const float* Wsvd; const float* bsvd;
    const float* Wq; const float* Wk; const float* Wv; const float* Wa;
    const float* W1; const float* W2;
    const float* bq; const float* bk; const float* bv; const float* ba;
    const float* b1; const float* b2;
    const float* ln1b; const float* ln2b; const float* ln1g; const float* ln2g;
    float* h; short* hb; short* bias; short* qb; short* kb; short* vtb;
    short* obb; short* Wt;
};

// residual+LN epilogue. val[f][r] includes residual + gemm + bias; wave covers
// cols wave*64 + f*16 + c.
__device__ __forceinline__ void ln_store(
    float val[4][4], int m0, int wave, int quad, int c,
    const float* __restrict__ g, const float* __restrict__ lb,
    float* __restrict__ h, short* __restrict__ hb, char* smemp)
{
    float (*shs)[16][2] = (float(*)[16][2])smemp;
    float ps[4] = {0.f,0.f,0.f,0.f}, ps2[4] = {0.f,0.f,0.f,0.f};
#pragma unroll
    for (int f = 0; f < 4; ++f)
#pragma unroll
        for (int r = 0; r < 4; ++r) { ps[r] += val[f][r]; ps2[r] += val[f][r]*val[f][r]; }
#pragma unroll
    for (int r = 0; r < 4; ++r)
#pragma unroll
        for (int off = 1; off < 16; off <<= 1) {
            ps[r]  += __shfl_xor(ps[r], off);
            ps2[r] += __shfl_xor(ps2[r], off);
        }
    if (c == 0)
#pragma unroll
        for (int r = 0; r < 4; ++r) {
            shs[wave][quad*4+r][0] = ps[r];
            shs[wave][quad*4+r][1] = ps2[r];
        }
    __syncthreads();
    float mu[4], rv[4];
#pragma unroll
    for (int r = 0; r < 4; ++r) {
        int rr = quad*4 + r;
        float ts = shs[0][rr][0] + shs[1][rr][0] + shs[2][rr][0] + shs[3][rr][0];
        float t2 = shs[0][rr][1] + shs[1][rr][1] + shs[2][rr][1] + shs[3][rr][1];
        float m = ts * (1.0f/DD);
        mu[r] = m;
        rv[r] = rsqrtf(t2 * (1.0f/DD) - m*m + EPSF);
    }
#pragma unroll
    for (int f = 0; f < 4; ++f) {
        int col = wave*64 + f*16 + c;
        float gg = g[col], bbv = lb[col];
#pragma unroll
        for (int r = 0; r < 4; ++r) {
            int row = m0 + quad*4 + r;
            float nv = (val[f][r] - mu[r]) * rv[r] * gg + bbv;
            h[(size_t)row*DD + col] = nv;
            hb[(size_t)row*DD + col] = (short)f2bf(nv);
        }
    }
}

__global__ __launch_bounds__(256, 3) void mega_kernel(MegaP p)
{
    cg::grid_group grid = cg::this_grid();
    int tid = threadIdx.x;
    int wave = tid >> 6, lane = tid & 63;
    int quad = lane >> 4, c = lane & 15;
    int blk = blockIdx.x;
    int G = gridDim.x;

    __shared__ __align__(16) char smem[18432];
    const f32x4 zero = {0.f, 0.f, 0.f, 0.f};

    // ================= stage 0: prologue ===================================
    for (int row = blk; row < MM; row += G) {
        int n = row & (NN - 1);
        int d = tid;
        int di = p.deg_in[n], dou = p.deg_out[n];
        float acc = p.x[(size_t)row*DD + d] + p.in_emb[(size_t)di*DD + d]
                  + p.out_emb[(size_t)dou*DD + d] + p.bsvd[d];
        const float* sv = &p.svd[n * 32];
#pragma unroll
        for (int j = 0; j < 32; ++j) {
            float v = sv[j];
            v = (j < 16) ? v : -v;
            acc += v * p.Wsvd[j*DD + d];
        }
        p.h[(size_t)row*DD + d] = acc;
        p.hb[(size_t)row*DD + d] = (short)f2bf(acc);
    }
    // ================= stage 0b: prep ======================================
    for (int u = blk; u < 640; u += G) {
        if (u < 384) {
            float (*t)[65] = (float(*)[65])smem;
            __syncthreads();               // protect vs previous unit's reads
            int z = u >> 4, tile = u & 15;
            int name = z >> 2;
            const float* srcs[6] = {p.Wq, p.Wk, p.Wv, p.Wa, p.W1, p.W2};
            const float* W = srcs[name] + (size_t)(z & 3) * DD * DD;
            short* dst = p.Wt + (size_t)z * DD * DD;
            int r0 = (tile >> 2) * 64, c0 = (tile & 3) * 64;
#pragma unroll
            for (int i = 0; i < 16; ++i) {
                int idx = i * 256 + tid;
                int r = idx >> 6, cc = idx & 63;
                t[r][cc] = W[(size_t)(r0 + r)*DD + c0 + cc];
            }
            __syncthreads();
#pragma unroll
            for (int i = 0; i < 16; ++i) {
                int idx = i * 256 + tid;
                int n = idx >> 6, k = idx & 63;
                dst[(size_t)(c0 + n)*DD + r0 + k] = (short)f2bf(t[k][n]);
            }
        } else {
            int tt = (u - 384) * 256 + tid;       // (q16, kt, lane)
            int ln = tt & 63, kt = (tt >> 6) & 15, q16 = tt >> 10;
            int qd = ln >> 4, cc = ln & 15;
            unsigned buf[8][8];
#pragma unroll
            for (int j = 0; j < 16; ++j) {
                int f = j >> 2, r = j & 3;
                int row = q16*16 + qd*4 + r;
                int col = kt*64 + f*16 + cc;
                int pp = p.sp[row*NN + col];
#pragma unroll
                for (int hh = 0; hh < 8; ++hh) {
                    unsigned short uu = f2bf(p.spemb[pp*8 + hh]);
                    if (j & 1) buf[hh][j >> 1] |= ((unsigned)uu) << 16;
                    else       buf[hh][j >> 1] = uu;
                }
            }
#pragma unroll
            for (int hh = 0; hh < 8; ++hh) {
                uint4* dst = (uint4*)&p.bias[(((size_t)hh*64 + q16)*16 + kt)*1024 + (size_t)ln*16];
                dst[0] = make_uint4(buf[hh][0], buf[hh][1], buf[hh][2], buf[hh][3]);
                dst[1] = make_uint4(buf[hh][4], buf[hh][5], buf[hh][6], buf[hh][7]);
            }
        }
    }
    grid.sync();

    // ================= layers ==============================================
    for (int l = 0; l < LL; ++l) {
        const float* bq_l = p.bq + l*DD;
        const float* bk_l = p.bk + l*DD;
        const float* bv_l = p.bv + l*DD;
        const float* ba_l = p.ba + l*DD;
        const float* b1_l = p.b1 + l*DD;
        const float* b2_l = p.b2 + l*DD;
        const float* g1_l = p.ln1g + l*DD; const float* lb1_l = p.ln1b + l*DD;
        const float* g2_l = p.ln2g + l*DD; const float* lb2_l = p.ln2b + l*DD;
        const short* Wtq = p.Wt + (size_t)(0*4 + l)*DD*DD;
        const short* Wtk = p.Wt + (size_t)(1*4 + l)*DD*DD;
        const short* Wtv = p.Wt + (size_t)(2*4 + l)*DD*DD;
        const short* Wta = p.Wt + (size_t)(3*4 + l)*DD*DD;
        const short* Wt1 = p.Wt + (size_t)(4*4 + l)*DD*DD;
        const short* Wt2 = p.Wt + (size_t)(5*4 + l)*DD*DD;

        // ---- QKV: 3072 units ----
        for (int u = blk; u < 3072; u += G) {
            int mt = u & 255, nt = (u >> 8) & 3, z = u >> 10;
            const short* Wz = (z == 0) ? Wtq : (z == 1) ? Wtk : Wtv;
            const float* bz = (z == 0) ? bq_l : (z == 1) ? bk_l : bv_l;
            int m0 = mt * 16;
            int n0 = nt * 64 + wave * 16;
            f32x4 acc = zero;
            const short* Ap = &p.hb[(size_t)(m0 + c) * DD];
#pragma unroll
            for (int ks = 0; ks < 8; ++ks) {
                short8 af = *(const short8*)&Ap[ks*32 + quad*8];
                short8 bf = *(const short8*)&Wz[(size_t)(n0 + c)*DD + ks*32 + quad*8];
                acc = __builtin_amdgcn_mfma_f32_16x16x32_bf16(af, bf, acc, 0, 0, 0);
            }
            int b = m0 >> 10;
            int tok0 = (m0 & (NN - 1)) + quad * 4;
            int col = n0 + c;
            int head = col >> 5, dk = col & 31;
            int bh = b * 8 + head;
            float bv2 = bz[col];
            if (z == 2) {
                ushort4 pk;
                pk.x = f2bf(acc[0] + bv2); pk.y = f2bf(acc[1] + bv2);
                pk.z = f2bf(acc[2] + bv2); pk.w = f2bf(acc[3] + bv2);
                *(ushort4*)&p.vtb[((size_t)bh*DKK + dk)*NN + tok0] = pk;
            } else {
                short* out = (z == 0) ? p.qb : p.kb;
                float sc = (z == 0) ? 0.17677669529663687f : 1.0f;
#pragma unroll
                for (int r = 0; r < 4; ++r)
                    out[((size_t)bh*NN + tok0 + r)*DKK + dk] =
                        (short)f2bf((acc[r] + bv2) * sc);
            }
        }
        grid.sync();

        // ---- ATTN: 2048 units; waves split K range ----
        {
            short (*Pl)[16][72] = (short(*)[16][72])smem;            // 9216 B
            float (*Om)[16][32] = (float(*)[16][32])(smem + 9216);   // 8192 B
            float (*Ml)[16][2]  = (float(*)[16][2]) (smem + 17408);  // 512 B
            short (*P)[72] = Pl[wave];
            for (int u = blk; u < 2048; u += G) {
                int qt = u & 63, bh = u >> 6;
                int b = bh >> 3, hd = bh & 7;
                int q0 = qt * 16;

                short8 qf = *(const short8*)&p.qb[((size_t)bh*NN + q0 + c)*DKK + quad*8];
                float m_i[4], l_i[4];
                f32x4 Oa0 = zero, Oa1 = zero;
#pragma unroll
                for (int r = 0; r < 4; ++r) { m_i[r] = -1e30f; l_i[r] = 0.f; }

#pragma unroll
                for (int j = 0; j < 4; ++j) {
                    int kti = wave * 4 + j;
                    int kt = kti * 64;
                    f32x4 s[4];
#pragma unroll
                    for (int f = 0; f < 4; ++f) {
                        short8 kf = *(const short8*)&p.kb[((size_t)bh*NN + kt + f*16 + c)*DKK + quad*8];
                        s[f] = __builtin_amdgcn_mfma_f32_16x16x32_bf16(qf, kf, zero, 0, 0, 0);
                    }
                    const short* bp = &p.bias[(((size_t)hd*64 + qt)*16 + kti)*1024 + (size_t)lane*16];
                    short8 b0 = *(const short8*)bp;
                    short8 b1 = *(const short8*)(bp + 8);
#pragma unroll
                    for (int f = 0; f < 4; ++f)
#pragma unroll
                        for (int r = 0; r < 4; ++r) {
                            int jj = f*4 + r;
                            unsigned short uu = (unsigned short)((jj < 8) ? b0[jj] : b1[jj - 8]);
                            s[f][r] += bf2f(uu);
                        }
#pragma unroll
                    for (int r = 0; r < 4; ++r) {
                        float mt2 = fmaxf(fmaxf(s[0][r], s[1][r]), fmaxf(s[2][r], s[3][r]));
#pragma unroll
                        for (int off = 1; off < 16; off <<= 1) mt2 = fmaxf(mt2, __shfl_xor(mt2, off));
                        float mn = fmaxf(m_i[r], mt2);
                        float alpha = __expf(m_i[r] - mn);
                        m_i[r] = mn;
                        float rs = 0.f;
#pragma unroll
                        for (int f = 0; f < 4; ++f) {
                            float pr = __expf(s[f][r] - mn);
                            s[f][r] = pr;
                            rs += pr;
                        }
#pragma unroll
                        for (int off = 1; off < 16; off <<= 1) rs += __shfl_xor(rs, off);
                        l_i[r] = l_i[r] * alpha + rs;
                        Oa0[r] *= alpha;
                        Oa1[r] *= alpha;
                    }
#pragma unroll
                    for (int f = 0; f < 4; ++f)
#pragma unroll
                        for (int r = 0; r < 4; ++r)
                            P[quad*4 + r][f*16 + c] = (short)f2bf(s[f][r]);
#pragma unroll
                    for (int kc = 0; kc < 2; ++kc) {
                        short8 pf = *(const short8*)&P[c][kc*32 + quad*8];
                        short8 vf0 = *(const short8*)&p.vtb[((size_t)bh*DKK + 0  + c)*NN + kt + kc*32 + quad*8];
                        short8 vf1 = *(const short8*)&p.vtb[((size_t)bh*DKK + 16 + c)*NN + kt + kc*32 + quad*8];
                        Oa0 = __builtin_amdgcn_mfma_f32_16x16x32_bf16(pf, vf0, Oa0, 0, 0, 0);
                        Oa1 = __builtin_amdgcn_mfma_f32_16x16x32_bf16(pf, vf1, Oa1, 0, 0, 0);
                    }
                }
                __syncthreads();   // protect Om/Ml vs previous unit's reads
                if (c == 0)
#pragma unroll
                    for (int r = 0; r < 4; ++r) {
                        Ml[wave][quad*4 + r][0] = m_i[r];
                        Ml[wave][quad*4 + r][1] = l_i[r];
                    }
#pragma unroll
                for (int r = 0; r < 4; ++r) {
                    Om[wave][quad*4 + r][c]      = Oa0[r];
                    Om[wave][quad*4 + r][16 + c] = Oa1[r];
                }
                __syncthreads();
                int row = tid >> 4;
                float mg = fmaxf(fmaxf(Ml[0][row][0], Ml[1][row][0]),
                                 fmaxf(Ml[2][row][0], Ml[3][row][0]));
                float sc[4], lg = 0.f;
#pragma unroll
                for (int w = 0; w < 4; ++w) {
                    sc[w] = __expf(Ml[w][row][0] - mg);
                    lg += Ml[w][row][1] * sc[w];
                }
                float invl = 1.0f / lg;
                int col0 = (tid & 15) * 2;
                float o0 = 0.f, o1 = 0.f;
#pragma unroll
                for (int w = 0; w < 4; ++w) {
                    o0 += Om[w][row][col0] * sc[w];
                    o1 += Om[w][row][col0 + 1] * sc[w];
                }
                ushort2 pk;
                pk.x = f2bf(o0 * invl);
                pk.y = f2bf(o1 * invl);
                *(ushort2*)&p.obb[((size_t)b*NN + q0 + row)*DD + hd*DKK + col0] = pk;
            }
        }
        grid.sync();

        // ---- Wa + residual + LN: 256 units ----
        for (int u = blk; u < 256; u += G) {
            int m0 = u * 16;
            const short* Ap = &p.obb[(size_t)(m0 + c) * DD];
            f32x4 acc[4] = {zero, zero, zero, zero};
#pragma unroll
            for (int ks = 0; ks < 8; ++ks) {
                short8 af = *(const short8*)&Ap[ks*32 + quad*8];
#pragma unroll
                for (int f = 0; f < 4; ++f) {
                    short8 bf = *(const short8*)&Wta[(size_t)(wave*64 + f*16 + c)*DD + ks*32 + quad*8];
                    acc[f] = __builtin_amdgcn_mfma_f32_16x16x32_bf16(af, bf, acc[f], 0, 0, 0);
                }
            }
            float val[4][4];
#pragma unroll
            for (int f = 0; f < 4; ++f) {
                int col = wave*64 + f*16 + c;
                float bv = ba_l[col];
#pragma unroll
                for (int r = 0; r < 4; ++r)
                    val[f][r] = p.h[(size_t)(m0 + quad*4 + r)*DD + col] + acc[f][r] + bv;
            }
            ln_store(val, m0, wave, quad, c, g1_l, lb1_l, p.h, p.hb, smem);
        }
        grid.sync();

        // ---- FFN fused: W1+ReLU (to LDS) then W2 + residual + LN ----
        for (int u = blk; u < 256; u += G) {
            short (*t1s)[264] = (short(*)[264])smem;            // 8448 B
            char* shsmem = smem + 8448;                         // 512 B stats
            int m0 = u * 16;
            const short* Ap = &p.hb[(size_t)(m0 + c) * DD];
#pragma unroll
            for (int f = 0; f < 4; ++f) {
                int n0 = wave*64 + f*16;
                f32x4 acc = zero;
#pragma unroll
                for (int ks = 0; ks < 8; ++ks) {
                    short8 af = *(const short8*)&Ap[ks*32 + quad*8];
                    short8 bf = *(const short8*)&Wt1[(size_t)(n0 + c)*DD + ks*32 + quad*8];
                    acc = __builtin_amdgcn_mfma_f32_16x16x32_bf16(af, bf, acc, 0, 0, 0);
                }
                float bv = b1_l[n0 + c];
#pragma unroll
                for (int r = 0; r < 4; ++r)
                    t1s[quad*4 + r][n0 + c] = (short)f2bf(fmaxf(acc[r] + bv, 0.f));
            }
            __syncthreads();
            f32x4 acc2[4] = {zero, zero, zero, zero};
#pragma unroll
            for (int ks = 0; ks < 8; ++ks) {
                short8 af = *(const short8*)&t1s[c][ks*32 + quad*8];
#pragma unroll
                for (int f = 0; f < 4; ++f) {
                    short8 bf = *(const short8*)&Wt2[(size_t)(wave*64 + f*16 + c)*DD + ks*32 + quad*8];
                    acc2[f] = __builtin_amdgcn_mfma_f32_16x16x32_bf16(af, bf, acc2[f], 0, 0, 0);
                }
            }
            float val[4][4];
#pragma unroll
            for (int f = 0; f < 4; ++f) {
                int col = wave*64 + f*16 + c;
                float bv = b2_l[col];
#pragma unroll
                for (int r = 0; r < 4; ++r)
                    val[f][r] = p.h[(size_t)(m0 + quad*4 + r)*DD + col] + acc2[f][r] + bv;
            }
            __syncthreads();
            ln_store(val, m0, wave, quad, c, g2_l, lb2_l, p.h, p.hb, shsmem);
        }
        grid.sync();
    }
}

// ======================= fallback pipeline (R4, known-good) =================
__global__ __launch_bounds__(256) void prologue_kernel(
    const float* __restrict__ x, const int* __restrict__ deg_in,
    const int* __restrict__ deg_out, const float* __restrict__ svd,
    const float* __restrict__ in_emb, const float* __restrict__ out_emb,
    const float* __restrict__ Wsvd, const float* __restrict__ bsvd,
    float* __restrict__ h, short* __restrict__ hb)
{
    int blk = blockIdx.x;
    int n = blk & (NN - 1);
    int d = threadIdx.x;
    __shared__ float pos[32];
    if (d < 32) {
        float v = svd[n * 32 + d];
        pos[d] = (d < 16) ? v : -v;
    }
    __syncthreads();
    int di = deg_in[n], dou = deg_out[n];
    float acc = x[(size_t)blk * DD + d] + in_emb[(size_t)di * DD + d]
              + out_emb[(size_t)dou * DD + d] + bsvd[d];
#pragma unroll
    for (int j = 0; j < 32; ++j) acc += pos[j] * Wsvd[j * DD + d];
    h[(size_t)blk * DD + d] = acc;
    hb[(size_t)blk * DD + d] = (short)f2bf(acc);
}

__global__ __launch_bounds__(256) void prep_kernel(
    const float* __restrict__ Wq, const float* __restrict__ Wk,
    const float* __restrict__ Wv, const float* __restrict__ Wa,
    const float* __restrict__ W1, const float* __restrict__ W2,
    short* __restrict__ Wt,
    const int* __restrict__ sp, const float* __restrict__ emb,
    short* __restrict__ bsw)
{
    __shared__ float t[64][65];
    int tid = threadIdx.x;
    int blk = blockIdx.x;
    if (blk < 384) {
        int z = blk >> 4, tile = blk & 15;
        int name = z >> 2;
        const float* srcs[6] = {Wq, Wk, Wv, Wa, W1, W2};
        const float* W = srcs[name] + (size_t)(z & 3) * DD * DD;
        short* dst = Wt + (size_t)z * DD * DD;
        int r0 = (tile >> 2) * 64, c0 = (tile & 3) * 64;
#pragma unroll
        for (int i = 0; i < 16; ++i) {
            int idx = i * 256 + tid;
            int r = idx >> 6, cc = idx & 63;
            t[r][cc] = W[(size_t)(r0 + r) * DD + c0 + cc];
        }
        __syncthreads();
#pragma unroll
        for (int i = 0; i < 16; ++i) {
            int idx = i * 256 + tid;
            int n = idx >> 6, k = idx & 63;
            dst[(size_t)(c0 + n) * DD + r0 + k] = (short)f2bf(t[k][n]);
        }
    } else {
        int tt = (blk - 384) * 256 + tid;
        int ln = tt & 63, kt = (tt >> 6) & 15, q16 = tt >> 10;
        int qd = ln >> 4, cc = ln & 15;
        unsigned buf[8][8];
#pragma unroll
        for (int j = 0; j < 16; ++j) {
            int f = j >> 2, r = j & 3;
            int row = q16 * 16 + qd * 4 + r;
            int col = kt * 64 + f * 16 + cc;
            int pp = sp[row * NN + col];
#pragma unroll
            for (int hh = 0; hh < 8; ++hh) {
                unsigned short u = f2bf(emb[pp * 8 + hh]);
                if (j & 1) buf[hh][j >> 1] |= ((unsigned)u) << 16;
                else       buf[hh][j >> 1] = u;
            }
        }
#pragma unroll
        for (int hh = 0; hh < 8; ++hh) {
            uint4* dst = (uint4*)&bsw[(((size_t)hh * 64 + q16) * 16 + kt) * 1024 + (size_t)ln * 16];
            dst[0] = make_uint4(buf[hh][0], buf[hh][1], buf[hh][2], buf[hh][3]);
            dst[1] = make_uint4(buf[hh][4], buf[hh][5], buf[hh][6], buf[hh][7]);
        }
    }
}

__global__ __launch_bounds__(256) void gemm_relu_kernel(
    const short* __restrict__ A, const short* __restrict__ Wt,
    const float* __restrict__ bias, short* __restrict__ outb)
{
    int tid = threadIdx.x, wave = tid >> 6, lane = tid & 63;
    int quad = lane >> 4, c = lane & 15;
    int m0 = blockIdx.x * 16;
    int n0 = blockIdx.y * 64 + wave * 16;
    f32x4 acc = {0.f, 0.f, 0.f, 0.f};
    const short* Ap = &A[(size_t)(m0 + c) * DD];
#pragma unroll
    for (int ks = 0; ks < 8; ++ks) {
        short8 af = *(const short8*)&Ap[ks * 32 + quad * 8];
        short8 bf = *(const short8*)&Wt[(size_t)(n0 + c) * DD + ks * 32 + quad * 8];
        acc = __builtin_amdgcn_mfma_f32_16x16x32_bf16(af, bf, acc, 0, 0, 0);
    }
    int col = n0 + c;
    float bv = bias[col];
#pragma unroll
    for (int r = 0; r < 4; ++r)
        outb[(size_t)(m0 + quad * 4 + r) * DD + col] = (short)f2bf(fmaxf(acc[r] + bv, 0.f));
}

__global__ __launch_bounds__(512) void gemm_ln_kernel(
    const short* __restrict__ A, const short* __restrict__ Wt,
    const float* __restrict__ bias, const float* __restrict__ g,
    const float* __restrict__ lb,
    float* __restrict__ h, short* __restrict__ hb)
{
    int tid = threadIdx.x, wave = tid >> 6, lane = tid & 63;
    int quad = lane >> 4, c = lane & 15;
    int m0 = blockIdx.x * 16;
    int n0 = wave * 32;
    f32x4 acc[2] = {{0.f,0.f,0.f,0.f},{0.f,0.f,0.f,0.f}};
    const short* Ap = &A[(size_t)(m0 + c) * DD];
#pragma unroll
    for (int ks = 0; ks < 8; ++ks) {
        short8 af = *(const short8*)&Ap[ks * 32 + quad * 8];
#pragma unroll
        for (int f = 0; f < 2; ++f) {
            short8 bf = *(const short8*)&Wt[(size_t)(n0 + f * 16 + c) * DD + ks * 32 + quad * 8];
            acc[f] = __builtin_amdgcn_mfma_f32_16x16x32_bf16(af, bf, acc[f], 0, 0, 0);
        }
    }
    float val[2][4];
    float ps[4] = {0.f,0.f,0.f,0.f}, ps2[4] = {0.f,0.f,0.f,0.f};
#pragma unroll
    for (int f = 0; f < 2; ++f) {
        int col = n0 + f * 16 + c;
        float bv = bias[col];
#pragma unroll
        for (int r = 0; r < 4; ++r) {
            int row = m0 + quad * 4 + r;
            float v = h[(size_t)row * DD + col] + acc[f][r] + bv;
            val[f][r] = v;
            ps[r] += v;
            ps2[r] += v * v;
        }
    }
#pragma unroll
    for (int r = 0; r < 4; ++r)
#pragma unroll
        for (int off = 1; off < 16; off <<= 1) {
            ps[r]  += __shfl_xor(ps[r], off);
            ps2[r] += __shfl_xor(ps2[r], off);
        }
    __shared__ float shs[8][16][2];
    if (c == 0)
#pragma unroll
        for (int r = 0; r < 4; ++r) {
            shs[wave][quad * 4 + r][0] = ps[r];
            shs[wave][quad * 4 + r][1] = ps2[r];
        }
    __syncthreads();
    float mu[4], rvar[4];
#pragma unroll
    for (int r = 0; r < 4; ++r) {
        int rr = quad * 4 + r;
        float ts = 0.f, t2 = 0.f;
#pragma unroll
        for (int w = 0; w < 8; ++w) { ts += shs[w][rr][0]; t2 += shs[w][rr][1]; }
        float m = ts * (1.0f / DD);
        mu[r] = m;
        rvar[r] = rsqrtf(t2 * (1.0f / DD) - m * m + EPSF);
    }
#pragma unroll
    for (int f = 0; f < 2; ++f) {
        int col = n0 + f * 16 + c;
        float gg = g[col], bbv = lb[col];
#pragma unroll
        for (int r = 0; r < 4; ++r) {
            int row = m0 + quad * 4 + r;
            float nv = (val[f][r] - mu[r]) * rvar[r] * gg + bbv;
            h[(size_t)row * DD + col] = nv;
            hb[(size_t)row * DD + col] = (short)f2bf(nv);
        }
    }
}

__global__ __launch_bounds__(256) void gemm_qkv_kernel(
    const short* __restrict__ A,
    const short* __restrict__ Wtq, const short* __restrict__ Wtk,
    const short* __restrict__ Wtv,
    const float* __restrict__ bq, const float* __restrict__ bk,
    const float* __restrict__ bv,
    short* __restrict__ qo, short* __restrict__ ko, short* __restrict__ vo)
{
    int z = blockIdx.z;
    const short* Wt = (z == 0) ? Wtq : (z == 1) ? Wtk : Wtv;
    const float* bs = (z == 0) ? bq : (z == 1) ? bk : bv;
    int tid = threadIdx.x, wave = tid >> 6, lane = tid & 63;
    int quad = lane >> 4, c = lane & 15;
    int m0 = blockIdx.x * 16;
    int n0 = blockIdx.y * 64 + wave * 16;
    f32x4 acc = {0.f, 0.f, 0.f, 0.f};
    const short* Ap = &A[(size_t)(m0 + c) * DD];
#pragma unroll
    for (int ks = 0; ks < 8; ++ks) {
        short8 af = *(const short8*)&Ap[ks * 32 + quad * 8];
        short8 bf = *(const short8*)&Wt[(size_t)(n0 + c) * DD + ks * 32 + quad * 8];
        acc = __builtin_amdgcn_mfma_f32_16x16x32_bf16(af, bf, acc, 0, 0, 0);
    }
    int b = m0 >> 10;
    int tok0 = (m0 & (NN - 1)) + quad * 4;
    int col = n0 + c;
    int head = col >> 5, dk = col & 31;
    int bh = b * 8 + head;
    float bv2 = bs[col];
    const float scale = 0.17677669529663687f;
    if (z == 2) {
        ushort4 pk;
        pk.x = f2bf(acc[0] + bv2); pk.y = f2bf(acc[1] + bv2);
        pk.z = f2bf(acc[2] + bv2); pk.w = f2bf(acc[3] + bv2);
        *(ushort4*)&vo[((size_t)bh * DKK + dk) * NN + tok0] = pk;
    } else {
        short* out = (z == 0) ? qo : ko;
        float sc = (z == 0) ? scale : 1.0f;
#pragma unroll
        for (int r = 0; r < 4; ++r)
            out[((size_t)bh * NN + tok0 + r) * DKK + dk] =
                (short)f2bf((acc[r] + bv2) * sc);
    }
}

__global__ __launch_bounds__(256) void attn_kernel(
    const short* __restrict__ q, const short* __restrict__ k,
    const short* __restrict__ vt, const short* __restrict__ bsw,
    short* __restrict__ o)
{
    int bh = blockIdx.y;
    int b = bh >> 3, h = bh & 7;
    int t = blockIdx.x;
    int tid = threadIdx.x, wave = tid >> 6, lane = tid & 63;
    int quad = lane >> 4, c = lane & 15;
    int q0 = t * 16;
    __shared__ short Pl[4][16][72];
    __shared__ float Om[4][16][32];
    __shared__ float Ml[4][16][2];
    short (*P)[72] = Pl[wave];
    short8 qf = *(const short8*)&q[((size_t)bh * NN + q0 + c) * DKK + quad * 8];
    float m_i[4], l_i[4];
    f32x4 Oa0 = {0.f, 0.f, 0.f, 0.f};
    f32x4 Oa1 = {0.f, 0.f, 0.f, 0.f};
#pragma unroll
    for (int r = 0; r < 4; ++r) { m_i[r] = -1e30f; l_i[r] = 0.f; }
    const f32x4 zero = {0.f, 0.f, 0.f, 0.f};
#pragma unroll
    for (int j = 0; j < 4; ++j) {
        int kti = wave * 4 + j;
        int kt = kti * 64;
        f32x4 s[4];
#pragma unroll
        for (int f = 0; f < 4; ++f) {
            short8 kf = *(const short8*)&k[((size_t)bh * NN + kt + f * 16 + c) * DKK + quad * 8];
            s[f] = __builtin_amdgcn_mfma_f32_16x16x32_bf16(qf, kf, zero, 0, 0, 0);
        }
        const short* bp = &bsw[(((size_t)h * 64 + t) * 16 + kti) * 1024 + (size_t)lane * 16];
        short8 b0 = *(const short8*)bp;
        short8 b1 = *(const short8*)(bp + 8);
#pragma unroll
        for (int f = 0; f < 4; ++f)
#pragma unroll
            for (int r = 0; r < 4; ++r) {
                int jj = f * 4 + r;
                unsigned short uu = (unsigned short)((jj < 8) ? b0[jj] : b1[jj - 8]);
                s[f][r] += bf2f(uu);
            }
#pragma unroll
        for (int r = 0; r < 4; ++r) {
            float mt2 = fmaxf(fmaxf(s[0][r], s[1][r]), fmaxf(s[2][r], s[3][r]));
#pragma unroll
            for (int off = 1; off < 16; off <<= 1) mt2 = fmaxf(mt2, __shfl_xor(mt2, off));
            float mn = fmaxf(m_i[r], mt2);
            float alpha = __expf(m_i[r] - mn);
            m_i[r] = mn;
            float rs = 0.f;
#pragma unroll
            for (int f = 0; f < 4; ++f) {
                float pr = __expf(s[f][r] - mn);
                s[f][r] = pr;
                rs += pr;
            }
#pragma unroll
            for (int off = 1; off < 16; off <<= 1) rs += __shfl_xor(rs, off);
            l_i[r] = l_i[r] * alpha + rs;
            Oa0[r] *= alpha;
            Oa1[r] *= alpha;
        }
#pragma unroll
        for (int f = 0; f < 4; ++f)
#pragma unroll
            for (int r = 0; r < 4; ++r)
                P[quad * 4 + r][f * 16 + c] = (short)f2bf(s[f][r]);
#pragma unroll
        for (int kc = 0; kc < 2; ++kc) {
            short8 pf = *(const short8*)&P[c][kc * 32 + quad * 8];
            short8 vf0 = *(const short8*)&vt[((size_t)bh * DKK + 0  + c) * NN + kt + kc * 32 + quad * 8];
            short8 vf1 = *(const short8*)&vt[((size_t)bh * DKK + 16 + c) * NN + kt + kc * 32 + quad * 8];
            Oa0 = __builtin_amdgcn_mfma_f32_16x16x32_bf16(pf, vf0, Oa0, 0, 0, 0);
            Oa1 = __builtin_amdgcn_mfma_f32_16x16x32_bf16(pf, vf1, Oa1, 0, 0, 0);
        }
    }
    if (c == 0)
#pragma unroll
        for (int r = 0; r < 4; ++r) {
            Ml[wave][quad * 4 + r][0] = m_i[r];
            Ml[wave][quad * 4 + r][1] = l_i[r];
        }
#pragma unroll
    for (int r = 0; r < 4; ++r) {
        Om[wave][quad * 4 + r][c]      = Oa0[r];
        Om[wave][quad * 4 + r][16 + c] = Oa1[r];
    }
    __syncthreads();
    int row = tid >> 4;
    float mg = fmaxf(fmaxf(Ml[0][row][0], Ml[1][row][0]),
                     fmaxf(Ml[2][row][0], Ml[3][row][0]));
    float sc[4], lg = 0.f;
#pragma unroll
    for (int w = 0; w < 4; ++w) {
        sc[w] = __expf(Ml[w][row][0] - mg);
        lg += Ml[w][row][1] * sc[w];
    }
    float invl = 1.0f / lg;
    int col0 = (tid & 15) * 2;
    float o0 = 0.f, o1 = 0.f;
#pragma unroll
    for (int w = 0; w < 4; ++w) {
        o0 += Om[w][row][col0] * sc[w];
        o1 += Om[w][row][col0 + 1] * sc[w];
    }
    ushort2 pk;
    pk.x = f2bf(o0 * invl);
    pk.y = f2bf(o1 * invl);
    *(ushort2*)&o[((size_t)b * NN + q0 + row) * DD + h * DKK + col0] = pk;
}

// ---------------------------------------------------------------------------
extern "C" void kernel_launch(void* const* d_in, const int* in_sizes, int n_in,
                              void* d_out, int out_size, void* d_ws, size_t ws_size,
                              hipStream_t stream)
{
    MegaP prm;
    prm.x       = (const float*)d_in[0];
    prm.deg_in  = (const int*)d_in[1];
    prm.deg_out = (const int*)d_in[2];
    prm.sp      = (const int*)d_in[3];
    prm.svd     = (const float*)d_in[4];
    prm.in_emb  = (const float*)d_in[5];
    prm.out_emb = (const float*)d_in[6];
    prm.spemb   = (const float*)d_in[7];
    prm.Wsvd    = (const float*)d_in[8];
    prm.bsvd    = (const float*)d_in[9];
    prm.Wq = (const float*)d_in[10];
    prm.Wk = (const float*)d_in[11];
    prm.Wv = (const float*)d_in[12];
    prm.Wa = (const float*)d_in[13];
    prm.W1 = (const float*)d_in[14];
    prm.W2 = (const float*)d_in[15];
    prm.bq = (const float*)d_in[16];
    prm.bk = (const float*)d_in[17];
    prm.bv = (const float*)d_in[18];
    prm.ba = (const float*)d_in[19];
    prm.b1 = (const float*)d_in[20];
    prm.b2 = (const float*)d_in[21];
    prm.ln1b = (const float*)d_in[22];
    prm.ln2b = (const float*)d_in[23];
    prm.ln1g = (const float*)d_in[24];
    prm.ln2g = (const float*)d_in[25];

    char* ws = (char*)d_ws;
    prm.h    = (float*)d_out;
    prm.bias = (short*)ws;                          // 16 MB swizzled bf16 bias
    prm.qb   = (short*)(ws + ((size_t)16 << 20));   // 2 MB
    prm.kb   = (short*)(ws + ((size_t)18 << 20));   // 2 MB
    prm.vtb  = (short*)(ws + ((size_t)20 << 20));   // 2 MB
    prm.obb  = (short*)(ws + ((size_t)22 << 20));   // 2 MB
    short* t1 = (short*)(ws + ((size_t)24 << 20));  // 2 MB (fallback only)
    prm.hb   = (short*)(ws + ((size_t)26 << 20));   // 2 MB bf16 shadow of h
    prm.Wt   = (short*)(ws + ((size_t)28 << 20));   // 3 MB transposed weights

    // ---- cooperative mega-kernel path, occupancy-guarded ----
    int ma = 0;
    hipError_t qe = hipOccupancyMaxActiveBlocksPerMultiprocessor(
        &ma, (const void*)mega_kernel, 256, 0);
    if (qe == hipSuccess && ma >= 1) {
        int bpc = ma > 3 ? 3 : ma;
        void* args[] = { &prm };
        hipError_t e = hipLaunchCooperativeKernel(
            (const void*)mega_kernel, dim3(256 * bpc), dim3(256), args, 0, stream);
        if (e == hipSuccess) return;
    }

    // ---- fallback: R4 multi-kernel pipeline ----
    prologue_kernel<<<MM, 256, 0, stream>>>(prm.x, prm.deg_in, prm.deg_out,
        prm.svd, prm.in_emb, prm.out_emb, prm.Wsvd, prm.bsvd, prm.h, prm.hb);
    prep_kernel<<<640, 256, 0, stream>>>(prm.Wq, prm.Wk, prm.Wv, prm.Wa,
        prm.W1, prm.W2, prm.Wt, prm.sp, prm.spemb, prm.bias);
    const size_t WSZ = (size_t)DD * DD;
    for (int l = 0; l < LL; ++l) {
        const size_t bo = (size_t)l * DD;
        const short* Wtq = prm.Wt + (0 * 4 + l) * WSZ;
        const short* Wtk = prm.Wt + (1 * 4 + l) * WSZ;
        const short* Wtv = prm.Wt + (2 * 4 + l) * WSZ;
        const short* Wta = prm.Wt + (3 * 4 + l) * WSZ;
        const short* Wt1 = prm.Wt + (4 * 4 + l) * WSZ;
        const short* Wt2 = prm.Wt + (5 * 4 + l) * WSZ;
        gemm_qkv_kernel<<<dim3(MM / 16, 4, 3), 256, 0, stream>>>(
            prm.hb, Wtq, Wtk, Wtv, prm.bq + bo, prm.bk + bo, prm.bv + bo,
            prm.qb, prm.kb, prm.vtb);
        attn_kernel<<<dim3(NN / 16, BB * HH), 256, 0, stream>>>(
            prm.qb, prm.kb, prm.vtb, prm.bias, prm.obb);
        gemm_ln_kernel<<<MM / 16, 512, 0, stream>>>(
            prm.obb, Wta, prm.ba + bo, prm.ln1g + bo, prm.ln1b + bo, prm.h, prm.hb);
        gemm_relu_kernel<<<dim3(MM / 16, 4), 256, 0, stream>>>(
            prm.hb, Wt1, prm.b1 + bo, t1);
        gemm_ln_kernel<<<MM / 16, 512, 0, stream>>>(
            t1, Wt2, prm.b2 + bo, prm.ln2g + bo, prm.ln2b + bo, prm.h, prm.hb);
    }
}

// Round 8
// 403.864 us; speedup vs baseline: 3.4516x; 3.4516x over previous
//
#include <hip/hip_runtime.h>
#include <hip/hip_bf16.h>
#include <math.h>

#define NN 1024
#define BB 4
#define HH 8
#define DD 256
#define LL 4
#define DKK 32
#define MM 4096
#define EPSF 1e-6f

typedef __attribute__((ext_vector_type(8))) short short8;
typedef __attribute__((ext_vector_type(4))) float f32x4;

__device__ __forceinline__ unsigned short f2bf(float f) {
    __hip_bfloat16 h = __float2bfloat16(f);
    return *(unsigned short*)&h;
}
__device__ __forceinline__ float bf2f(unsigned short u) {
    unsigned v = ((unsigned)u) << 16;
    return __builtin_bit_cast(float, v);
}

// ---------------------------------------------------------------------------
// init: every block does one prologue row; blocks 0..383 also transpose a
// weight tile; blocks 384..639 also swizzle a bias slab.
// ---------------------------------------------------------------------------
__global__ __launch_bounds__(256) void init_kernel(
    const float* __restrict__ x, const int* __restrict__ deg_in,
    const int* __restrict__ deg_out, const float* __restrict__ svd,
    const float* __restrict__ in_emb, const float* __restrict__ out_emb,
    const float* __restrict__ Wsvd, const float* __restrict__ bsvd,
    const float* __restrict__ Wq, const float* __restrict__ Wk,
    const float* __restrict__ Wv, const float* __restrict__ Wa,
    const float* __restrict__ W1, const float* __restrict__ W2,
    const int* __restrict__ sp, const float* __restrict__ spemb,
    float* __restrict__ h, short* __restrict__ hb,
    short* __restrict__ Wt, short* __restrict__ bsw)
{
    int blk = blockIdx.x;
    int tid = threadIdx.x;
    // ---- prologue row ----
    {
        int n = blk & (NN - 1);
        int di = deg_in[n], dou = deg_out[n];
        float acc = x[(size_t)blk * DD + tid] + in_emb[(size_t)di * DD + tid]
                  + out_emb[(size_t)dou * DD + tid] + bsvd[tid];
        const float* sv = &svd[n * 32];
#pragma unroll
        for (int j = 0; j < 32; ++j) {
            float v = sv[j];
            v = (j < 16) ? v : -v;
            acc += v * Wsvd[j * DD + tid];
        }
        h[(size_t)blk * DD + tid] = acc;
        hb[(size_t)blk * DD + tid] = (short)f2bf(acc);
    }
    // ---- prep work ----
    if (blk < 384) {
        __shared__ float t[64][65];
        int z = blk >> 4, tile = blk & 15;
        int name = z >> 2;
        const float* srcs[6] = {Wq, Wk, Wv, Wa, W1, W2};
        const float* W = srcs[name] + (size_t)(z & 3) * DD * DD;
        short* dst = Wt + (size_t)z * DD * DD;
        int r0 = (tile >> 2) * 64, c0 = (tile & 3) * 64;
#pragma unroll
        for (int i = 0; i < 16; ++i) {
            int idx = i * 256 + tid;
            int r = idx >> 6, cc = idx & 63;
            t[r][cc] = W[(size_t)(r0 + r) * DD + c0 + cc];
        }
        __syncthreads();
#pragma unroll
        for (int i = 0; i < 16; ++i) {
            int idx = i * 256 + tid;
            int n = idx >> 6, k = idx & 63;
            dst[(size_t)(c0 + n) * DD + r0 + k] = (short)f2bf(t[k][n]);
        }
    } else if (blk < 640) {
        int tt = (blk - 384) * 256 + tid;       // (q16, kt, lane)
        int ln = tt & 63, kt = (tt >> 6) & 15, q16 = tt >> 10;
        int qd = ln >> 4, cc = ln & 15;
        unsigned buf[8][8];
#pragma unroll
        for (int j = 0; j < 16; ++j) {
            int f = j >> 2, r = j & 3;
            int row = q16 * 16 + qd * 4 + r;
            int col = kt * 64 + f * 16 + cc;
            int pp = sp[row * NN + col];
#pragma unroll
            for (int hh = 0; hh < 8; ++hh) {
                unsigned short u = f2bf(spemb[pp * 8 + hh]);
                if (j & 1) buf[hh][j >> 1] |= ((unsigned)u) << 16;
                else       buf[hh][j >> 1] = u;
            }
        }
#pragma unroll
        for (int hh = 0; hh < 8; ++hh) {
            uint4* dst = (uint4*)&bsw[(((size_t)hh * 64 + q16) * 16 + kt) * 1024 + (size_t)ln * 16];
            dst[0] = make_uint4(buf[hh][0], buf[hh][1], buf[hh][2], buf[hh][3]);
            dst[1] = make_uint4(buf[hh][4], buf[hh][5], buf[hh][6], buf[hh][7]);
        }
    }
}

// ---------------------------------------------------------------------------
// QKV bf16 GEMM, wave = 16x16 tile. Grid (MM/16, 4, 3).
// ---------------------------------------------------------------------------
__global__ __launch_bounds__(256) void gemm_qkv_kernel(
    const short* __restrict__ A,
    const short* __restrict__ Wtq, const short* __restrict__ Wtk,
    const short* __restrict__ Wtv,
    const float* __restrict__ bq, const float* __restrict__ bk,
    const float* __restrict__ bv,
    short* __restrict__ qo, short* __restrict__ ko, short* __restrict__ vo)
{
    int z = blockIdx.z;
    const short* Wt = (z == 0) ? Wtq : (z == 1) ? Wtk : Wtv;
    const float* bs = (z == 0) ? bq : (z == 1) ? bk : bv;
    int tid = threadIdx.x, wave = tid >> 6, lane = tid & 63;
    int quad = lane >> 4, c = lane & 15;
    int m0 = blockIdx.x * 16;
    int n0 = blockIdx.y * 64 + wave * 16;
    f32x4 acc = {0.f, 0.f, 0.f, 0.f};
    const short* Ap = &A[(size_t)(m0 + c) * DD];
#pragma unroll
    for (int ks = 0; ks < 8; ++ks) {
        short8 af = *(const short8*)&Ap[ks * 32 + quad * 8];
        short8 bf = *(const short8*)&Wt[(size_t)(n0 + c) * DD + ks * 32 + quad * 8];
        acc = __builtin_amdgcn_mfma_f32_16x16x32_bf16(af, bf, acc, 0, 0, 0);
    }
    int b = m0 >> 10;
    int tok0 = (m0 & (NN - 1)) + quad * 4;
    int col = n0 + c;
    int head = col >> 5, dk = col & 31;
    int bh = b * 8 + head;
    float bv2 = bs[col];
    const float scale = 0.17677669529663687f;
    if (z == 2) {
        ushort4 pk;
        pk.x = f2bf(acc[0] + bv2); pk.y = f2bf(acc[1] + bv2);
        pk.z = f2bf(acc[2] + bv2); pk.w = f2bf(acc[3] + bv2);
        *(ushort4*)&vo[((size_t)bh * DKK + dk) * NN + tok0] = pk;
    } else {
        short* out = (z == 0) ? qo : ko;
        float sc = (z == 0) ? scale : 1.0f;
#pragma unroll
        for (int r = 0; r < 4; ++r)
            out[((size_t)bh * NN + tok0 + r) * DKK + dk] =
                (short)f2bf((acc[r] + bv2) * sc);
    }
}

// ---------------------------------------------------------------------------
// MFMA flash attention v3 (R4, proven): grid (64, 32); waves split K range,
// partials merged in LDS.
// ---------------------------------------------------------------------------
__global__ __launch_bounds__(256) void attn_kernel(
    const short* __restrict__ q, const short* __restrict__ k,
    const short* __restrict__ vt, const short* __restrict__ bsw,
    short* __restrict__ o)
{
    int bh = blockIdx.y;
    int b = bh >> 3, h = bh & 7;
    int t = blockIdx.x;
    int tid = threadIdx.x, wave = tid >> 6, lane = tid & 63;
    int quad = lane >> 4, c = lane & 15;
    int q0 = t * 16;
    __shared__ short Pl[4][16][72];
    __shared__ float Om[4][16][32];
    __shared__ float Ml[4][16][2];
    short (*P)[72] = Pl[wave];
    short8 qf = *(const short8*)&q[((size_t)bh * NN + q0 + c) * DKK + quad * 8];
    float m_i[4], l_i[4];
    f32x4 Oa0 = {0.f, 0.f, 0.f, 0.f};
    f32x4 Oa1 = {0.f, 0.f, 0.f, 0.f};
#pragma unroll
    for (int r = 0; r < 4; ++r) { m_i[r] = -1e30f; l_i[r] = 0.f; }
    const f32x4 zero = {0.f, 0.f, 0.f, 0.f};
#pragma unroll
    for (int j = 0; j < 4; ++j) {
        int kti = wave * 4 + j;
        int kt = kti * 64;
        f32x4 s[4];
#pragma unroll
        for (int f = 0; f < 4; ++f) {
            short8 kf = *(const short8*)&k[((size_t)bh * NN + kt + f * 16 + c) * DKK + quad * 8];
            s[f] = __builtin_amdgcn_mfma_f32_16x16x32_bf16(qf, kf, zero, 0, 0, 0);
        }
        const short* bp = &bsw[(((size_t)h * 64 + t) * 16 + kti) * 1024 + (size_t)lane * 16];
        short8 b0 = *(const short8*)bp;
        short8 b1 = *(const short8*)(bp + 8);
#pragma unroll
        for (int f = 0; f < 4; ++f)
#pragma unroll
            for (int r = 0; r < 4; ++r) {
                int jj = f * 4 + r;
                unsigned short uu = (unsigned short)((jj < 8) ? b0[jj] : b1[jj - 8]);
                s[f][r] += bf2f(uu);
            }
#pragma unroll
        for (int r = 0; r < 4; ++r) {
            float mt2 = fmaxf(fmaxf(s[0][r], s[1][r]), fmaxf(s[2][r], s[3][r]));
#pragma unroll
            for (int off = 1; off < 16; off <<= 1) mt2 = fmaxf(mt2, __shfl_xor(mt2, off));
            float mn = fmaxf(m_i[r], mt2);
            float alpha = __expf(m_i[r] - mn);
            m_i[r] = mn;
            float rs = 0.f;
#pragma unroll
            for (int f = 0; f < 4; ++f) {
                float pr = __expf(s[f][r] - mn);
                s[f][r] = pr;
                rs += pr;
            }
#pragma unroll
            for (int off = 1; off < 16; off <<= 1) rs += __shfl_xor(rs, off);
            l_i[r] = l_i[r] * alpha + rs;
            Oa0[r] *= alpha;
            Oa1[r] *= alpha;
        }
#pragma unroll
        for (int f = 0; f < 4; ++f)
#pragma unroll
            for (int r = 0; r < 4; ++r)
                P[quad * 4 + r][f * 16 + c] = (short)f2bf(s[f][r]);
#pragma unroll
        for (int kc = 0; kc < 2; ++kc) {
            short8 pf = *(const short8*)&P[c][kc * 32 + quad * 8];
            short8 vf0 = *(const short8*)&vt[((size_t)bh * DKK + 0  + c) * NN + kt + kc * 32 + quad * 8];
            short8 vf1 = *(const short8*)&vt[((size_t)bh * DKK + 16 + c) * NN + kt + kc * 32 + quad * 8];
            Oa0 = __builtin_amdgcn_mfma_f32_16x16x32_bf16(pf, vf0, Oa0, 0, 0, 0);
            Oa1 = __builtin_amdgcn_mfma_f32_16x16x32_bf16(pf, vf1, Oa1, 0, 0, 0);
        }
    }
    if (c == 0)
#pragma unroll
        for (int r = 0; r < 4; ++r) {
            Ml[wave][quad * 4 + r][0] = m_i[r];
            Ml[wave][quad * 4 + r][1] = l_i[r];
        }
#pragma unroll
    for (int r = 0; r < 4; ++r) {
        Om[wave][quad * 4 + r][c]      = Oa0[r];
        Om[wave][quad * 4 + r][16 + c] = Oa1[r];
    }
    __syncthreads();
    int row = tid >> 4;
    float mg = fmaxf(fmaxf(Ml[0][row][0], Ml[1][row][0]),
                     fmaxf(Ml[2][row][0], Ml[3][row][0]));
    float sc[4], lg = 0.f;
#pragma unroll
    for (int w = 0; w < 4; ++w) {
        sc[w] = __expf(Ml[w][row][0] - mg);
        lg += Ml[w][row][1] * sc[w];
    }
    float invl = 1.0f / lg;
    int col0 = (tid & 15) * 2;
    float o0 = 0.f, o1 = 0.f;
#pragma unroll
    for (int w = 0; w < 4; ++w) {
        o0 += Om[w][row][col0] * sc[w];
        o1 += Om[w][row][col0 + 1] * sc[w];
    }
    ushort2 pk;
    pk.x = f2bf(o0 * invl);
    pk.y = f2bf(o1 * invl);
    *(ushort2*)&o[((size_t)b * NN + q0 + row) * DD + h * DKK + col0] = pk;
}

// ---------------------------------------------------------------------------
// Fused post-attention: Wa GEMM + res + LN1, then W1+ReLU (LDS), then
// W2 + res + LN2. Block = 16 rows, 4 waves (wave covers 64 cols). Grid 256.
// ---------------------------------------------------------------------------
__global__ __launch_bounds__(256) void post_kernel(
    const short* __restrict__ obb,
    const short* __restrict__ Wta, const short* __restrict__ Wt1,
    const short* __restrict__ Wt2,
    const float* __restrict__ ba, const float* __restrict__ b1,
    const float* __restrict__ b2,
    const float* __restrict__ g1, const float* __restrict__ lb1,
    const float* __restrict__ g2, const float* __restrict__ lb2,
    float* __restrict__ h, short* __restrict__ hb)
{
    int tid = threadIdx.x, wave = tid >> 6, lane = tid & 63;
    int quad = lane >> 4, c = lane & 15;
    int m0 = blockIdx.x * 16;

    __shared__ short t_in[16][264];
    __shared__ short t1s[16][264];
    __shared__ float shs[4][16][2];
    const f32x4 zero = {0.f, 0.f, 0.f, 0.f};

    // ---- Wa GEMM ----
    f32x4 acc[4] = {zero, zero, zero, zero};
    {
        const short* Ap = &obb[(size_t)(m0 + c) * DD];
#pragma unroll
        for (int ks = 0; ks < 8; ++ks) {
            short8 af = *(const short8*)&Ap[ks * 32 + quad * 8];
#pragma unroll
            for (int f = 0; f < 4; ++f) {
                short8 bf = *(const short8*)&Wta[(size_t)(wave * 64 + f * 16 + c) * DD + ks * 32 + quad * 8];
                acc[f] = __builtin_amdgcn_mfma_f32_16x16x32_bf16(af, bf, acc[f], 0, 0, 0);
            }
        }
    }
    // ---- residual + LN1 stats ----
    float val[4][4];
    float ps[4] = {0.f,0.f,0.f,0.f}, ps2[4] = {0.f,0.f,0.f,0.f};
#pragma unroll
    for (int f = 0; f < 4; ++f) {
        int col = wave * 64 + f * 16 + c;
        float bv = ba[col];
#pragma unroll
        for (int r = 0; r < 4; ++r) {
            float v = h[(size_t)(m0 + quad * 4 + r) * DD + col] + acc[f][r] + bv;
            val[f][r] = v;
            ps[r] += v;
            ps2[r] += v * v;
        }
    }
#pragma unroll
    for (int r = 0; r < 4; ++r)
#pragma unroll
        for (int off = 1; off < 16; off <<= 1) {
            ps[r]  += __shfl_xor(ps[r], off);
            ps2[r] += __shfl_xor(ps2[r], off);
        }
    if (c == 0)
#pragma unroll
        for (int r = 0; r < 4; ++r) {
            shs[wave][quad * 4 + r][0] = ps[r];
            shs[wave][quad * 4 + r][1] = ps2[r];
        }
    __syncthreads();
    float res[4][4];
#pragma unroll
    for (int r = 0; r < 4; ++r) {
        int rr = quad * 4 + r;
        float ts = shs[0][rr][0] + shs[1][rr][0] + shs[2][rr][0] + shs[3][rr][0];
        float t2 = shs[0][rr][1] + shs[1][rr][1] + shs[2][rr][1] + shs[3][rr][1];
        float mu = ts * (1.0f / DD);
        float rv = rsqrtf(t2 * (1.0f / DD) - mu * mu + EPSF);
#pragma unroll
        for (int f = 0; f < 4; ++f) {
            int col = wave * 64 + f * 16 + c;
            float nv = (val[f][r] - mu) * rv * g1[col] + lb1[col];
            res[f][r] = nv;
            h[(size_t)(m0 + rr) * DD + col] = nv;
            short bfv = (short)f2bf(nv);
            hb[(size_t)(m0 + rr) * DD + col] = bfv;
            t_in[rr][col] = bfv;
        }
    }
    __syncthreads();
    // ---- W1 + ReLU -> t1s ----
#pragma unroll
    for (int f = 0; f < 4; ++f) {
        int n0 = wave * 64 + f * 16;
        f32x4 a1 = zero;
#pragma unroll
        for (int ks = 0; ks < 8; ++ks) {
            short8 af = *(const short8*)&t_in[c][ks * 32 + quad * 8];
            short8 bf = *(const short8*)&Wt1[(size_t)(n0 + c) * DD + ks * 32 + quad * 8];
            a1 = __builtin_amdgcn_mfma_f32_16x16x32_bf16(af, bf, a1, 0, 0, 0);
        }
        float bv = b1[n0 + c];
#pragma unroll
        for (int r = 0; r < 4; ++r)
            t1s[quad * 4 + r][n0 + c] = (short)f2bf(fmaxf(a1[r] + bv, 0.f));
    }
    __syncthreads();
    // ---- W2 GEMM from t1s ----
    f32x4 acc2[4] = {zero, zero, zero, zero};
#pragma unroll
    for (int ks = 0; ks < 8; ++ks) {
        short8 af = *(const short8*)&t1s[c][ks * 32 + quad * 8];
#pragma unroll
        for (int f = 0; f < 4; ++f) {
            short8 bf = *(const short8*)&Wt2[(size_t)(wave * 64 + f * 16 + c) * DD + ks * 32 + quad * 8];
            acc2[f] = __builtin_amdgcn_mfma_f32_16x16x32_bf16(af, bf, acc2[f], 0, 0, 0);
        }
    }
    // ---- residual + LN2 ----
    float ps_2[4] = {0.f,0.f,0.f,0.f}, ps2_2[4] = {0.f,0.f,0.f,0.f};
#pragma unroll
    for (int f = 0; f < 4; ++f) {
        int col = wave * 64 + f * 16 + c;
        float bv = b2[col];
#pragma unroll
        for (int r = 0; r < 4; ++r) {
            float v = res[f][r] + acc2[f][r] + bv;
            val[f][r] = v;
            ps_2[r] += v;
            ps2_2[r] += v * v;
        }
    }
#pragma unroll
    for (int r = 0; r < 4; ++r)
#pragma unroll
        for (int off = 1; off < 16; off <<= 1) {
            ps_2[r]  += __shfl_xor(ps_2[r], off);
            ps2_2[r] += __shfl_xor(ps2_2[r], off);
        }
    __syncthreads();          // LN1 shs reads complete before overwrite
    if (c == 0)
#pragma unroll
        for (int r = 0; r < 4; ++r) {
            shs[wave][quad * 4 + r][0] = ps_2[r];
            shs[wave][quad * 4 + r][1] = ps2_2[r];
        }
    __syncthreads();
#pragma unroll
    for (int r = 0; r < 4; ++r) {
        int rr = quad * 4 + r;
        float ts = shs[0][rr][0] + shs[1][rr][0] + shs[2][rr][0] + shs[3][rr][0];
        float t2 = shs[0][rr][1] + shs[1][rr][1] + shs[2][rr][1] + shs[3][rr][1];
        float mu = ts * (1.0f / DD);
        float rv = rsqrtf(t2 * (1.0f / DD) - mu * mu + EPSF);
#pragma unroll
        for (int f = 0; f < 4; ++f) {
            int col = wave * 64 + f * 16 + c;
            float nv = (val[f][r] - mu) * rv * g2[col] + lb2[col];
            h[(size_t)(m0 + rr) * DD + col] = nv;
            hb[(size_t)(m0 + rr) * DD + col] = (short)f2bf(nv);
        }
    }
}

// ---------------------------------------------------------------------------
extern "C" void kernel_launch(void* const* d_in, const int* in_sizes, int n_in,
                              void* d_out, int out_size, void* d_ws, size_t ws_size,
                              hipStream_t stream)
{
    const float* x       = (const float*)d_in[0];
    const int*   deg_in  = (const int*)d_in[1];
    const int*   deg_out = (const int*)d_in[2];
    const int*   sp      = (const int*)d_in[3];
    const float* svd     = (const float*)d_in[4];
    const float* in_emb  = (const float*)d_in[5];
    const float* out_emb = (const float*)d_in[6];
    const float* spemb   = (const float*)d_in[7];
    const float* Wsvd    = (const float*)d_in[8];
    const float* bsvd    = (const float*)d_in[9];
    const float* Wq = (const float*)d_in[10];
    const float* Wk = (const float*)d_in[11];
    const float* Wv = (const float*)d_in[12];
    const float* Wa = (const float*)d_in[13];
    const float* W1 = (const float*)d_in[14];
    const float* W2 = (const float*)d_in[15];
    const float* bq = (const float*)d_in[16];
    const float* bk = (const float*)d_in[17];
    const float* bv = (const float*)d_in[18];
    const float* ba = (const float*)d_in[19];
    const float* b1 = (const float*)d_in[20];
    const float* b2 = (const float*)d_in[21];
    const float* ln1b = (const float*)d_in[22];
    const float* ln2b = (const float*)d_in[23];
    const float* ln1g = (const float*)d_in[24];
    const float* ln2g = (const float*)d_in[25];

    float* h = (float*)d_out;
    char*  ws = (char*)d_ws;
    short* bias = (short*)ws;                         // 16 MB swizzled bf16 bias
    short* qb   = (short*)(ws + ((size_t)16 << 20));  // 2 MB
    short* kb   = (short*)(ws + ((size_t)18 << 20));  // 2 MB
    short* vtb  = (short*)(ws + ((size_t)20 << 20));  // 2 MB
    short* obb  = (short*)(ws + ((size_t)22 << 20));  // 2 MB
    short* hb   = (short*)(ws + ((size_t)26 << 20));  // 2 MB bf16 shadow of h
    short* Wt   = (short*)(ws + ((size_t)28 << 20));  // 3 MB transposed weights

    init_kernel<<<MM, 256, 0, stream>>>(x, deg_in, deg_out, svd, in_emb,
        out_emb, Wsvd, bsvd, Wq, Wk, Wv, Wa, W1, W2, sp, spemb, h, hb, Wt, bias);

    const size_t WSZ = (size_t)DD * DD;
    for (int l = 0; l < LL; ++l) {
        const size_t bo = (size_t)l * DD;
        const short* Wtq = Wt + (0 * 4 + l) * WSZ;
        const short* Wtk = Wt + (1 * 4 + l) * WSZ;
        const short* Wtv = Wt + (2 * 4 + l) * WSZ;
        const short* Wta = Wt + (3 * 4 + l) * WSZ;
        const short* Wt1 = Wt + (4 * 4 + l) * WSZ;
        const short* Wt2 = Wt + (5 * 4 + l) * WSZ;

        gemm_qkv_kernel<<<dim3(MM / 16, 4, 3), 256, 0, stream>>>(
            hb, Wtq, Wtk, Wtv, bq + bo, bk + bo, bv + bo, qb, kb, vtb);
        attn_kernel<<<dim3(NN / 16, BB * HH), 256, 0, stream>>>(
            qb, kb, vtb, bias, obb);
        post_kernel<<<MM / 16, 256, 0, stream>>>(
            obb, Wta, Wt1, Wt2, ba + bo, b1 + bo, b2 + bo,
            ln1g + bo, ln1b + bo, ln2g + bo, ln2b + bo, h, hb);
    }
}

// Round 9
// 375.450 us; speedup vs baseline: 3.7128x; 1.0757x over previous
//
#include <hip/hip_runtime.h>
#include <hip/hip_bf16.h>
#include <math.h>

#define NN 1024
#define BB 4
#define HH 8
#define DD 256
#define LL 4
#define DKK 32
#define MM 4096
#define EPSF 1e-6f

typedef __attribute__((ext_vector_type(8))) short short8;
typedef __attribute__((ext_vector_type(4))) float f32x4;

__device__ __forceinline__ unsigned short f2bf(float f) {
    __hip_bfloat16 h = __float2bfloat16(f);
    return *(unsigned short*)&h;
}
__device__ __forceinline__ float bf2f(unsigned short u) {
    unsigned v = ((unsigned)u) << 16;
    return __builtin_bit_cast(float, v);
}

// ---------------------------------------------------------------------------
// init: every block does one prologue row; blocks 0..383 also transpose a
// weight tile; blocks 384..639 also swizzle a bias slab.
// ---------------------------------------------------------------------------
__global__ __launch_bounds__(256) void init_kernel(
    const float* __restrict__ x, const int* __restrict__ deg_in,
    const int* __restrict__ deg_out, const float* __restrict__ svd,
    const float* __restrict__ in_emb, const float* __restrict__ out_emb,
    const float* __restrict__ Wsvd, const float* __restrict__ bsvd,
    const float* __restrict__ Wq, const float* __restrict__ Wk,
    const float* __restrict__ Wv, const float* __restrict__ Wa,
    const float* __restrict__ W1, const float* __restrict__ W2,
    const int* __restrict__ sp, const float* __restrict__ spemb,
    float* __restrict__ h, short* __restrict__ hb,
    short* __restrict__ Wt, short* __restrict__ bsw)
{
    int blk = blockIdx.x;
    int tid = threadIdx.x;
    {
        int n = blk & (NN - 1);
        int di = deg_in[n], dou = deg_out[n];
        float acc = x[(size_t)blk * DD + tid] + in_emb[(size_t)di * DD + tid]
                  + out_emb[(size_t)dou * DD + tid] + bsvd[tid];
        const float* sv = &svd[n * 32];
#pragma unroll
        for (int j = 0; j < 32; ++j) {
            float v = sv[j];
            v = (j < 16) ? v : -v;
            acc += v * Wsvd[j * DD + tid];
        }
        h[(size_t)blk * DD + tid] = acc;
        hb[(size_t)blk * DD + tid] = (short)f2bf(acc);
    }
    if (blk < 384) {
        __shared__ float t[64][65];
        int z = blk >> 4, tile = blk & 15;
        int name = z >> 2;
        const float* srcs[6] = {Wq, Wk, Wv, Wa, W1, W2};
        const float* W = srcs[name] + (size_t)(z & 3) * DD * DD;
        short* dst = Wt + (size_t)z * DD * DD;
        int r0 = (tile >> 2) * 64, c0 = (tile & 3) * 64;
#pragma unroll
        for (int i = 0; i < 16; ++i) {
            int idx = i * 256 + tid;
            int r = idx >> 6, cc = idx & 63;
            t[r][cc] = W[(size_t)(r0 + r) * DD + c0 + cc];
        }
        __syncthreads();
#pragma unroll
        for (int i = 0; i < 16; ++i) {
            int idx = i * 256 + tid;
            int n = idx >> 6, k = idx & 63;
            dst[(size_t)(c0 + n) * DD + r0 + k] = (short)f2bf(t[k][n]);
        }
    } else if (blk < 640) {
        int tt = (blk - 384) * 256 + tid;       // (q16, kt, lane)
        int ln = tt & 63, kt = (tt >> 6) & 15, q16 = tt >> 10;
        int qd = ln >> 4, cc = ln & 15;
        unsigned buf[8][8];
#pragma unroll
        for (int j = 0; j < 16; ++j) {
            int f = j >> 2, r = j & 3;
            int row = q16 * 16 + qd * 4 + r;
            int col = kt * 64 + f * 16 + cc;
            int pp = sp[row * NN + col];
#pragma unroll
            for (int hh = 0; hh < 8; ++hh) {
                unsigned short u = f2bf(spemb[pp * 8 + hh]);
                if (j & 1) buf[hh][j >> 1] |= ((unsigned)u) << 16;
                else       buf[hh][j >> 1] = u;
            }
        }
#pragma unroll
        for (int hh = 0; hh < 8; ++hh) {
            uint4* dst = (uint4*)&bsw[(((size_t)hh * 64 + q16) * 16 + kt) * 1024 + (size_t)ln * 16];
            dst[0] = make_uint4(buf[hh][0], buf[hh][1], buf[hh][2], buf[hh][3]);
            dst[1] = make_uint4(buf[hh][4], buf[hh][5], buf[hh][6], buf[hh][7]);
        }
    }
}

// ---------------------------------------------------------------------------
// QKV bf16 GEMM (layer 0 only), wave = 16x16 tile. Grid (MM/16, 4, 3).
// ---------------------------------------------------------------------------
__global__ __launch_bounds__(256) void gemm_qkv_kernel(
    const short* __restrict__ A,
    const short* __restrict__ Wtq, const short* __restrict__ Wtk,
    const short* __restrict__ Wtv,
    const float* __restrict__ bq, const float* __restrict__ bk,
    const float* __restrict__ bv,
    short* __restrict__ qo, short* __restrict__ ko, short* __restrict__ vo)
{
    int z = blockIdx.z;
    const short* Wt = (z == 0) ? Wtq : (z == 1) ? Wtk : Wtv;
    const float* bs = (z == 0) ? bq : (z == 1) ? bk : bv;
    int tid = threadIdx.x, wave = tid >> 6, lane = tid & 63;
    int quad = lane >> 4, c = lane & 15;
    int m0 = blockIdx.x * 16;
    int n0 = blockIdx.y * 64 + wave * 16;
    f32x4 acc = {0.f, 0.f, 0.f, 0.f};
    const short* Ap = &A[(size_t)(m0 + c) * DD];
#pragma unroll
    for (int ks = 0; ks < 8; ++ks) {
        short8 af = *(const short8*)&Ap[ks * 32 + quad * 8];
        short8 bf = *(const short8*)&Wt[(size_t)(n0 + c) * DD + ks * 32 + quad * 8];
        acc = __builtin_amdgcn_mfma_f32_16x16x32_bf16(af, bf, acc, 0, 0, 0);
    }
    int b = m0 >> 10;
    int tok0 = (m0 & (NN - 1)) + quad * 4;
    int col = n0 + c;
    int head = col >> 5, dk = col & 31;
    int bh = b * 8 + head;
    float bv2 = bs[col];
    const float scale = 0.17677669529663687f;
    if (z == 2) {
        ushort4 pk;
        pk.x = f2bf(acc[0] + bv2); pk.y = f2bf(acc[1] + bv2);
        pk.z = f2bf(acc[2] + bv2); pk.w = f2bf(acc[3] + bv2);
        *(ushort4*)&vo[((size_t)bh * DKK + dk) * NN + tok0] = pk;
    } else {
        short* out = (z == 0) ? qo : ko;
        float sc = (z == 0) ? scale : 1.0f;
#pragma unroll
        for (int r = 0; r < 4; ++r)
            out[((size_t)bh * NN + tok0 + r) * DKK + dk] =
                (short)f2bf((acc[r] + bv2) * sc);
    }
}

// ---------------------------------------------------------------------------
// MFMA flash attention v3 (proven): grid (64, 32); waves split K range,
// partials merged in LDS.
// ---------------------------------------------------------------------------
__global__ __launch_bounds__(256) void attn_kernel(
    const short* __restrict__ q, const short* __restrict__ k,
    const short* __restrict__ vt, const short* __restrict__ bsw,
    short* __restrict__ o)
{
    int bh = blockIdx.y;
    int b = bh >> 3, h = bh & 7;
    int t = blockIdx.x;
    int tid = threadIdx.x, wave = tid >> 6, lane = tid & 63;
    int quad = lane >> 4, c = lane & 15;
    int q0 = t * 16;
    __shared__ short Pl[4][16][72];
    __shared__ float Om[4][16][32];
    __shared__ float Ml[4][16][2];
    short (*P)[72] = Pl[wave];
    short8 qf = *(const short8*)&q[((size_t)bh * NN + q0 + c) * DKK + quad * 8];
    float m_i[4], l_i[4];
    f32x4 Oa0 = {0.f, 0.f, 0.f, 0.f};
    f32x4 Oa1 = {0.f, 0.f, 0.f, 0.f};
#pragma unroll
    for (int r = 0; r < 4; ++r) { m_i[r] = -1e30f; l_i[r] = 0.f; }
    const f32x4 zero = {0.f, 0.f, 0.f, 0.f};
#pragma unroll
    for (int j = 0; j < 4; ++j) {
        int kti = wave * 4 + j;
        int kt = kti * 64;
        f32x4 s[4];
#pragma unroll
        for (int f = 0; f < 4; ++f) {
            short8 kf = *(const short8*)&k[((size_t)bh * NN + kt + f * 16 + c) * DKK + quad * 8];
            s[f] = __builtin_amdgcn_mfma_f32_16x16x32_bf16(qf, kf, zero, 0, 0, 0);
        }
        const short* bp = &bsw[(((size_t)h * 64 + t) * 16 + kti) * 1024 + (size_t)lane * 16];
        short8 b0 = *(const short8*)bp;
        short8 b1 = *(const short8*)(bp + 8);
#pragma unroll
        for (int f = 0; f < 4; ++f)
#pragma unroll
            for (int r = 0; r < 4; ++r) {
                int jj = f * 4 + r;
                unsigned short uu = (unsigned short)((jj < 8) ? b0[jj] : b1[jj - 8]);
                s[f][r] += bf2f(uu);
            }
#pragma unroll
        for (int r = 0; r < 4; ++r) {
            float mt2 = fmaxf(fmaxf(s[0][r], s[1][r]), fmaxf(s[2][r], s[3][r]));
#pragma unroll
            for (int off = 1; off < 16; off <<= 1) mt2 = fmaxf(mt2, __shfl_xor(mt2, off));
            float mn = fmaxf(m_i[r], mt2);
            float alpha = __expf(m_i[r] - mn);
            m_i[r] = mn;
            float rs = 0.f;
#pragma unroll
            for (int f = 0; f < 4; ++f) {
                float pr = __expf(s[f][r] - mn);
                s[f][r] = pr;
                rs += pr;
            }
#pragma unroll
            for (int off = 1; off < 16; off <<= 1) rs += __shfl_xor(rs, off);
            l_i[r] = l_i[r] * alpha + rs;
            Oa0[r] *= alpha;
            Oa1[r] *= alpha;
        }
#pragma unroll
        for (int f = 0; f < 4; ++f)
#pragma unroll
            for (int r = 0; r < 4; ++r)
                P[quad * 4 + r][f * 16 + c] = (short)f2bf(s[f][r]);
#pragma unroll
        for (int kc = 0; kc < 2; ++kc) {
            short8 pf = *(const short8*)&P[c][kc * 32 + quad * 8];
            short8 vf0 = *(const short8*)&vt[((size_t)bh * DKK + 0  + c) * NN + kt + kc * 32 + quad * 8];
            short8 vf1 = *(const short8*)&vt[((size_t)bh * DKK + 16 + c) * NN + kt + kc * 32 + quad * 8];
            Oa0 = __builtin_amdgcn_mfma_f32_16x16x32_bf16(pf, vf0, Oa0, 0, 0, 0);
            Oa1 = __builtin_amdgcn_mfma_f32_16x16x32_bf16(pf, vf1, Oa1, 0, 0, 0);
        }
    }
    if (c == 0)
#pragma unroll
        for (int r = 0; r < 4; ++r) {
            Ml[wave][quad * 4 + r][0] = m_i[r];
            Ml[wave][quad * 4 + r][1] = l_i[r];
        }
#pragma unroll
    for (int r = 0; r < 4; ++r) {
        Om[wave][quad * 4 + r][c]      = Oa0[r];
        Om[wave][quad * 4 + r][16 + c] = Oa1[r];
    }
    __syncthreads();
    int row = tid >> 4;
    float mg = fmaxf(fmaxf(Ml[0][row][0], Ml[1][row][0]),
                     fmaxf(Ml[2][row][0], Ml[3][row][0]));
    float sc[4], lg = 0.f;
#pragma unroll
    for (int w = 0; w < 4; ++w) {
        sc[w] = __expf(Ml[w][row][0] - mg);
        lg += Ml[w][row][1] * sc[w];
    }
    float invl = 1.0f / lg;
    int col0 = (tid & 15) * 2;
    float o0 = 0.f, o1 = 0.f;
#pragma unroll
    for (int w = 0; w < 4; ++w) {
        o0 += Om[w][row][col0] * sc[w];
        o1 += Om[w][row][col0 + 1] * sc[w];
    }
    ushort2 pk;
    pk.x = f2bf(o0 * invl);
    pk.y = f2bf(o1 * invl);
    *(ushort2*)&o[((size_t)b * NN + q0 + row) * DD + h * DKK + col0] = pk;
}

// ---------------------------------------------------------------------------
// Fused post-attention (+ optional next-layer QKV):
// Wa+res+LN1 -> W1+ReLU (LDS) -> W2+res+LN2 [-> QKV of next layer from LDS].
// Block = 16 rows, 4 waves. Grid 256.
// ---------------------------------------------------------------------------
template <int QKV>
__global__ __launch_bounds__(256) void post_kernel(
    const short* __restrict__ obb,
    const short* __restrict__ Wta, const short* __restrict__ Wt1,
    const short* __restrict__ Wt2,
    const float* __restrict__ ba, const float* __restrict__ b1,
    const float* __restrict__ b2,
    const float* __restrict__ g1, const float* __restrict__ lb1,
    const float* __restrict__ g2, const float* __restrict__ lb2,
    float* __restrict__ h, short* __restrict__ hb,
    const short* __restrict__ Wtqn, const short* __restrict__ Wtkn,
    const short* __restrict__ Wtvn,
    const float* __restrict__ bqn, const float* __restrict__ bkn,
    const float* __restrict__ bvn,
    short* __restrict__ qo, short* __restrict__ ko, short* __restrict__ vo)
{
    int tid = threadIdx.x, wave = tid >> 6, lane = tid & 63;
    int quad = lane >> 4, c = lane & 15;
    int m0 = blockIdx.x * 16;

    __shared__ short t_in[16][264];
    __shared__ short t1s[16][264];
    __shared__ float shs[4][16][2];
    const f32x4 zero = {0.f, 0.f, 0.f, 0.f};

    // ---- Wa GEMM ----
    f32x4 acc[4] = {zero, zero, zero, zero};
    {
        const short* Ap = &obb[(size_t)(m0 + c) * DD];
#pragma unroll
        for (int ks = 0; ks < 8; ++ks) {
            short8 af = *(const short8*)&Ap[ks * 32 + quad * 8];
#pragma unroll
            for (int f = 0; f < 4; ++f) {
                short8 bf = *(const short8*)&Wta[(size_t)(wave * 64 + f * 16 + c) * DD + ks * 32 + quad * 8];
                acc[f] = __builtin_amdgcn_mfma_f32_16x16x32_bf16(af, bf, acc[f], 0, 0, 0);
            }
        }
    }
    // ---- residual + LN1 ----
    float val[4][4];
    float ps[4] = {0.f,0.f,0.f,0.f}, ps2[4] = {0.f,0.f,0.f,0.f};
#pragma unroll
    for (int f = 0; f < 4; ++f) {
        int col = wave * 64 + f * 16 + c;
        float bv = ba[col];
#pragma unroll
        for (int r = 0; r < 4; ++r) {
            float v = h[(size_t)(m0 + quad * 4 + r) * DD + col] + acc[f][r] + bv;
            val[f][r] = v;
            ps[r] += v;
            ps2[r] += v * v;
        }
    }
#pragma unroll
    for (int r = 0; r < 4; ++r)
#pragma unroll
        for (int off = 1; off < 16; off <<= 1) {
            ps[r]  += __shfl_xor(ps[r], off);
            ps2[r] += __shfl_xor(ps2[r], off);
        }
    if (c == 0)
#pragma unroll
        for (int r = 0; r < 4; ++r) {
            shs[wave][quad * 4 + r][0] = ps[r];
            shs[wave][quad * 4 + r][1] = ps2[r];
        }
    __syncthreads();
    float res[4][4];
#pragma unroll
    for (int r = 0; r < 4; ++r) {
        int rr = quad * 4 + r;
        float ts = shs[0][rr][0] + shs[1][rr][0] + shs[2][rr][0] + shs[3][rr][0];
        float t2 = shs[0][rr][1] + shs[1][rr][1] + shs[2][rr][1] + shs[3][rr][1];
        float mu = ts * (1.0f / DD);
        float rv = rsqrtf(t2 * (1.0f / DD) - mu * mu + EPSF);
#pragma unroll
        for (int f = 0; f < 4; ++f) {
            int col = wave * 64 + f * 16 + c;
            float nv = (val[f][r] - mu) * rv * g1[col] + lb1[col];
            res[f][r] = nv;
            short bfv = (short)f2bf(nv);
            hb[(size_t)(m0 + rr) * DD + col] = bfv;
            t_in[rr][col] = bfv;
        }
    }
    __syncthreads();
    // ---- W1 + ReLU -> t1s ----
#pragma unroll
    for (int f = 0; f < 4; ++f) {
        int n0 = wave * 64 + f * 16;
        f32x4 a1 = zero;
#pragma unroll
        for (int ks = 0; ks < 8; ++ks) {
            short8 af = *(const short8*)&t_in[c][ks * 32 + quad * 8];
            short8 bf = *(const short8*)&Wt1[(size_t)(n0 + c) * DD + ks * 32 + quad * 8];
            a1 = __builtin_amdgcn_mfma_f32_16x16x32_bf16(af, bf, a1, 0, 0, 0);
        }
        float bv = b1[n0 + c];
#pragma unroll
        for (int r = 0; r < 4; ++r)
            t1s[quad * 4 + r][n0 + c] = (short)f2bf(fmaxf(a1[r] + bv, 0.f));
    }
    __syncthreads();
    // ---- W2 GEMM ----
    f32x4 acc2[4] = {zero, zero, zero, zero};
#pragma unroll
    for (int ks = 0; ks < 8; ++ks) {
        short8 af = *(const short8*)&t1s[c][ks * 32 + quad * 8];
#pragma unroll
        for (int f = 0; f < 4; ++f) {
            short8 bf = *(const short8*)&Wt2[(size_t)(wave * 64 + f * 16 + c) * DD + ks * 32 + quad * 8];
            acc2[f] = __builtin_amdgcn_mfma_f32_16x16x32_bf16(af, bf, acc2[f], 0, 0, 0);
        }
    }
    // ---- residual + LN2 ----
    float ps_2[4] = {0.f,0.f,0.f,0.f}, ps2_2[4] = {0.f,0.f,0.f,0.f};
#pragma unroll
    for (int f = 0; f < 4; ++f) {
        int col = wave * 64 + f * 16 + c;
        float bv = b2[col];
#pragma unroll
        for (int r = 0; r < 4; ++r) {
            float v = res[f][r] + acc2[f][r] + bv;
            val[f][r] = v;
            ps_2[r] += v;
            ps2_2[r] += v * v;
        }
    }
#pragma unroll
    for (int r = 0; r < 4; ++r)
#pragma unroll
        for (int off = 1; off < 16; off <<= 1) {
            ps_2[r]  += __shfl_xor(ps_2[r], off);
            ps2_2[r] += __shfl_xor(ps2_2[r], off);
        }
    __syncthreads();
    if (c == 0)
#pragma unroll
        for (int r = 0; r < 4; ++r) {
            shs[wave][quad * 4 + r][0] = ps_2[r];
            shs[wave][quad * 4 + r][1] = ps2_2[r];
        }
    __syncthreads();
#pragma unroll
    for (int r = 0; r < 4; ++r) {
        int rr = quad * 4 + r;
        float ts = shs[0][rr][0] + shs[1][rr][0] + shs[2][rr][0] + shs[3][rr][0];
        float t2 = shs[0][rr][1] + shs[1][rr][1] + shs[2][rr][1] + shs[3][rr][1];
        float mu = ts * (1.0f / DD);
        float rv = rsqrtf(t2 * (1.0f / DD) - mu * mu + EPSF);
#pragma unroll
        for (int f = 0; f < 4; ++f) {
            int col = wave * 64 + f * 16 + c;
            float nv = (val[f][r] - mu) * rv * g2[col] + lb2[col];
            h[(size_t)(m0 + rr) * DD + col] = nv;
            short bfv = (short)f2bf(nv);
            hb[(size_t)(m0 + rr) * DD + col] = bfv;
            t_in[rr][col] = bfv;           // stage for next-layer QKV
        }
    }
    if (QKV == 0) return;
    __syncthreads();
    // ---- next-layer QKV from t_in ----
    {
        int b = m0 >> 10;
        int tok0 = (m0 & (NN - 1)) + quad * 4;
        const short* Wz[3]  = {Wtqn, Wtkn, Wtvn};
        const float* bz[3]  = {bqn, bkn, bvn};
        const float scale = 0.17677669529663687f;
#pragma unroll
        for (int z = 0; z < 3; ++z) {
#pragma unroll
            for (int f = 0; f < 4; ++f) {
                int n0 = wave * 64 + f * 16;
                f32x4 aq = zero;
#pragma unroll
                for (int ks = 0; ks < 8; ++ks) {
                    short8 af = *(const short8*)&t_in[c][ks * 32 + quad * 8];
                    short8 bf = *(const short8*)&Wz[z][(size_t)(n0 + c) * DD + ks * 32 + quad * 8];
                    aq = __builtin_amdgcn_mfma_f32_16x16x32_bf16(af, bf, aq, 0, 0, 0);
                }
                int col = n0 + c;
                int head = col >> 5, dk = col & 31;
                int bh = b * 8 + head;
                float bv2 = bz[z][col];
                if (z == 2) {
                    ushort4 pk;
                    pk.x = f2bf(aq[0] + bv2); pk.y = f2bf(aq[1] + bv2);
                    pk.z = f2bf(aq[2] + bv2); pk.w = f2bf(aq[3] + bv2);
                    *(ushort4*)&vo[((size_t)bh * DKK + dk) * NN + tok0] = pk;
                } else {
                    short* out = (z == 0) ? qo : ko;
                    float sc = (z == 0) ? scale : 1.0f;
#pragma unroll
                    for (int r = 0; r < 4; ++r)
                        out[((size_t)bh * NN + tok0 + r) * DKK + dk] =
                            (short)f2bf((aq[r] + bv2) * sc);
                }
            }
        }
    }
}

// ---------------------------------------------------------------------------
extern "C" void kernel_launch(void* const* d_in, const int* in_sizes, int n_in,
                              void* d_out, int out_size, void* d_ws, size_t ws_size,
                              hipStream_t stream)
{
    const float* x       = (const float*)d_in[0];
    const int*   deg_in  = (const int*)d_in[1];
    const int*   deg_out = (const int*)d_in[2];
    const int*   sp      = (const int*)d_in[3];
    const float* svd     = (const float*)d_in[4];
    const float* in_emb  = (const float*)d_in[5];
    const float* out_emb = (const float*)d_in[6];
    const float* spemb   = (const float*)d_in[7];
    const float* Wsvd    = (const float*)d_in[8];
    const float* bsvd    = (const float*)d_in[9];
    const float* Wq = (const float*)d_in[10];
    const float* Wk = (const float*)d_in[11];
    const float* Wv = (const float*)d_in[12];
    const float* Wa = (const float*)d_in[13];
    const float* W1 = (const float*)d_in[14];
    const float* W2 = (const float*)d_in[15];
    const float* bq = (const float*)d_in[16];
    const float* bk = (const float*)d_in[17];
    const float* bv = (const float*)d_in[18];
    const float* ba = (const float*)d_in[19];
    const float* b1 = (const float*)d_in[20];
    const float* b2 = (const float*)d_in[21];
    const float* ln1b = (const float*)d_in[22];
    const float* ln2b = (const float*)d_in[23];
    const float* ln1g = (const float*)d_in[24];
    const float* ln2g = (const float*)d_in[25];

    float* h = (float*)d_out;
    char*  ws = (char*)d_ws;
    short* bias = (short*)ws;                         // 16 MB swizzled bf16 bias
    short* qb   = (short*)(ws + ((size_t)16 << 20));  // 2 MB
    short* kb   = (short*)(ws + ((size_t)18 << 20));  // 2 MB
    short* vtb  = (short*)(ws + ((size_t)20 << 20));  // 2 MB
    short* obb  = (short*)(ws + ((size_t)22 << 20));  // 2 MB
    short* hb   = (short*)(ws + ((size_t)26 << 20));  // 2 MB bf16 shadow of h
    short* Wt   = (short*)(ws + ((size_t)28 << 20));  // 3 MB transposed weights

    init_kernel<<<MM, 256, 0, stream>>>(x, deg_in, deg_out, svd, in_emb,
        out_emb, Wsvd, bsvd, Wq, Wk, Wv, Wa, W1, W2, sp, spemb, h, hb, Wt, bias);

    const size_t WSZ = (size_t)DD * DD;
    // layer-0 QKV
    gemm_qkv_kernel<<<dim3(MM / 16, 4, 3), 256, 0, stream>>>(
        hb, Wt + 0 * WSZ, Wt + 4 * WSZ, Wt + 8 * WSZ, bq, bk, bv, qb, kb, vtb);

    for (int l = 0; l < LL; ++l) {
        const size_t bo = (size_t)l * DD;
        const short* Wta = Wt + (3 * 4 + l) * WSZ;
        const short* Wt1 = Wt + (4 * 4 + l) * WSZ;
        const short* Wt2 = Wt + (5 * 4 + l) * WSZ;

        attn_kernel<<<dim3(NN / 16, BB * HH), 256, 0, stream>>>(
            qb, kb, vtb, bias, obb);

        if (l < LL - 1) {
            const size_t bo_n = (size_t)(l + 1) * DD;
            post_kernel<1><<<MM / 16, 256, 0, stream>>>(
                obb, Wta, Wt1, Wt2, ba + bo, b1 + bo, b2 + bo,
                ln1g + bo, ln1b + bo, ln2g + bo, ln2b + bo, h, hb,
                Wt + (0 * 4 + l + 1) * WSZ, Wt + (1 * 4 + l + 1) * WSZ,
                Wt + (2 * 4 + l + 1) * WSZ,
                bq + bo_n, bk + bo_n, bv + bo_n, qb, kb, vtb);
        } else {
            post_kernel<0><<<MM / 16, 256, 0, stream>>>(
                obb, Wta, Wt1, Wt2, ba + bo, b1 + bo, b2 + bo,
                ln1g + bo, ln1b + bo, ln2g + bo, ln2b + bo, h, hb,
                nullptr, nullptr, nullptr, nullptr, nullptr, nullptr,
                nullptr, nullptr, nullptr);
        }
    }
}

// Round 10
// 369.381 us; speedup vs baseline: 3.7738x; 1.0164x over previous
//
#include <hip/hip_runtime.h>
#include <hip/hip_bf16.h>
#include <math.h>

#define NN 1024
#define BB 4
#define HH 8
#define DD 256
#define LL 4
#define DKK 32
#define MM 4096
#define EPSF 1e-6f

typedef __attribute__((ext_vector_type(8))) short short8;
typedef __attribute__((ext_vector_type(4))) float f32x4;

__device__ __forceinline__ unsigned short f2bf(float f) {
    __hip_bfloat16 h = __float2bfloat16(f);
    return *(unsigned short*)&h;
}
__device__ __forceinline__ float bf2f(unsigned short u) {
    unsigned v = ((unsigned)u) << 16;
    return __builtin_bit_cast(float, v);
}

// ---------------------------------------------------------------------------
// init: every block does one prologue row; blocks 0..383 also transpose a
// weight tile; blocks 384..639 also swizzle a bias slab.
// ---------------------------------------------------------------------------
__global__ __launch_bounds__(256) void init_kernel(
    const float* __restrict__ x, const int* __restrict__ deg_in,
    const int* __restrict__ deg_out, const float* __restrict__ svd,
    const float* __restrict__ in_emb, const float* __restrict__ out_emb,
    const float* __restrict__ Wsvd, const float* __restrict__ bsvd,
    const float* __restrict__ Wq, const float* __restrict__ Wk,
    const float* __restrict__ Wv, const float* __restrict__ Wa,
    const float* __restrict__ W1, const float* __restrict__ W2,
    const int* __restrict__ sp, const float* __restrict__ spemb,
    float* __restrict__ h, short* __restrict__ hb,
    short* __restrict__ Wt, short* __restrict__ bsw)
{
    int blk = blockIdx.x;
    int tid = threadIdx.x;
    {
        int n = blk & (NN - 1);
        int di = deg_in[n], dou = deg_out[n];
        float acc = x[(size_t)blk * DD + tid] + in_emb[(size_t)di * DD + tid]
                  + out_emb[(size_t)dou * DD + tid] + bsvd[tid];
        const float* sv = &svd[n * 32];
#pragma unroll
        for (int j = 0; j < 32; ++j) {
            float v = sv[j];
            v = (j < 16) ? v : -v;
            acc += v * Wsvd[j * DD + tid];
        }
        h[(size_t)blk * DD + tid] = acc;
        hb[(size_t)blk * DD + tid] = (short)f2bf(acc);
    }
    if (blk < 384) {
        __shared__ float t[64][65];
        int z = blk >> 4, tile = blk & 15;
        int name = z >> 2;
        const float* srcs[6] = {Wq, Wk, Wv, Wa, W1, W2};
        const float* W = srcs[name] + (size_t)(z & 3) * DD * DD;
        short* dst = Wt + (size_t)z * DD * DD;
        int r0 = (tile >> 2) * 64, c0 = (tile & 3) * 64;
#pragma unroll
        for (int i = 0; i < 16; ++i) {
            int idx = i * 256 + tid;
            int r = idx >> 6, cc = idx & 63;
            t[r][cc] = W[(size_t)(r0 + r) * DD + c0 + cc];
        }
        __syncthreads();
#pragma unroll
        for (int i = 0; i < 16; ++i) {
            int idx = i * 256 + tid;
            int n = idx >> 6, k = idx & 63;
            dst[(size_t)(c0 + n) * DD + r0 + k] = (short)f2bf(t[k][n]);
        }
    } else if (blk < 640) {
        int tt = (blk - 384) * 256 + tid;       // (q16, kt, lane)
        int ln = tt & 63, kt = (tt >> 6) & 15, q16 = tt >> 10;
        int qd = ln >> 4, cc = ln & 15;
        unsigned buf[8][8];
#pragma unroll
        for (int j = 0; j < 16; ++j) {
            int f = j >> 2, r = j & 3;
            int row = q16 * 16 + qd * 4 + r;
            int col = kt * 64 + f * 16 + cc;
            int pp = sp[row * NN + col];
#pragma unroll
            for (int hh = 0; hh < 8; ++hh) {
                unsigned short u = f2bf(spemb[pp * 8 + hh]);
                if (j & 1) buf[hh][j >> 1] |= ((unsigned)u) << 16;
                else       buf[hh][j >> 1] = u;
            }
        }
#pragma unroll
        for (int hh = 0; hh < 8; ++hh) {
            uint4* dst = (uint4*)&bsw[(((size_t)hh * 64 + q16) * 16 + kt) * 1024 + (size_t)ln * 16];
            dst[0] = make_uint4(buf[hh][0], buf[hh][1], buf[hh][2], buf[hh][3]);
            dst[1] = make_uint4(buf[hh][4], buf[hh][5], buf[hh][6], buf[hh][7]);
        }
    }
}

// ---------------------------------------------------------------------------
// QKV bf16 GEMM (layer 0 only), wave = 16x16 tile. Grid (MM/16, 4, 3).
// ---------------------------------------------------------------------------
__global__ __launch_bounds__(256) void gemm_qkv_kernel(
    const short* __restrict__ A,
    const short* __restrict__ Wtq, const short* __restrict__ Wtk,
    const short* __restrict__ Wtv,
    const float* __restrict__ bq, const float* __restrict__ bk,
    const float* __restrict__ bv,
    short* __restrict__ qo, short* __restrict__ ko, short* __restrict__ vo)
{
    int z = blockIdx.z;
    const short* Wt = (z == 0) ? Wtq : (z == 1) ? Wtk : Wtv;
    const float* bs = (z == 0) ? bq : (z == 1) ? bk : bv;
    int tid = threadIdx.x, wave = tid >> 6, lane = tid & 63;
    int quad = lane >> 4, c = lane & 15;
    int m0 = blockIdx.x * 16;
    int n0 = blockIdx.y * 64 + wave * 16;
    f32x4 acc = {0.f, 0.f, 0.f, 0.f};
    const short* Ap = &A[(size_t)(m0 + c) * DD];
#pragma unroll
    for (int ks = 0; ks < 8; ++ks) {
        short8 af = *(const short8*)&Ap[ks * 32 + quad * 8];
        short8 bf = *(const short8*)&Wt[(size_t)(n0 + c) * DD + ks * 32 + quad * 8];
        acc = __builtin_amdgcn_mfma_f32_16x16x32_bf16(af, bf, acc, 0, 0, 0);
    }
    int b = m0 >> 10;
    int tok0 = (m0 & (NN - 1)) + quad * 4;
    int col = n0 + c;
    int head = col >> 5, dk = col & 31;
    int bh = b * 8 + head;
    float bv2 = bs[col];
    const float scale = 0.17677669529663687f;
    if (z == 2) {
        ushort4 pk;
        pk.x = f2bf(acc[0] + bv2); pk.y = f2bf(acc[1] + bv2);
        pk.z = f2bf(acc[2] + bv2); pk.w = f2bf(acc[3] + bv2);
        *(ushort4*)&vo[((size_t)bh * DKK + dk) * NN + tok0] = pk;
    } else {
        short* out = (z == 0) ? qo : ko;
        float sc = (z == 0) ? scale : 1.0f;
#pragma unroll
        for (int r = 0; r < 4; ++r)
            out[((size_t)bh * NN + tok0 + r) * DKK + dk] =
                (short)f2bf((acc[r] + bv2) * sc);
    }
}

// ---------------------------------------------------------------------------
// MFMA flash attention v3 (proven): grid (64, 32); waves split K range,
// partials merged in LDS.
// ---------------------------------------------------------------------------
__global__ __launch_bounds__(256) void attn_kernel(
    const short* __restrict__ q, const short* __restrict__ k,
    const short* __restrict__ vt, const short* __restrict__ bsw,
    short* __restrict__ o)
{
    int bh = blockIdx.y;
    int b = bh >> 3, h = bh & 7;
    int t = blockIdx.x;
    int tid = threadIdx.x, wave = tid >> 6, lane = tid & 63;
    int quad = lane >> 4, c = lane & 15;
    int q0 = t * 16;
    __shared__ short Pl[4][16][72];
    __shared__ float Om[4][16][32];
    __shared__ float Ml[4][16][2];
    short (*P)[72] = Pl[wave];
    short8 qf = *(const short8*)&q[((size_t)bh * NN + q0 + c) * DKK + quad * 8];
    float m_i[4], l_i[4];
    f32x4 Oa0 = {0.f, 0.f, 0.f, 0.f};
    f32x4 Oa1 = {0.f, 0.f, 0.f, 0.f};
#pragma unroll
    for (int r = 0; r < 4; ++r) { m_i[r] = -1e30f; l_i[r] = 0.f; }
    const f32x4 zero = {0.f, 0.f, 0.f, 0.f};
#pragma unroll
    for (int j = 0; j < 4; ++j) {
        int kti = wave * 4 + j;
        int kt = kti * 64;
        f32x4 s[4];
#pragma unroll
        for (int f = 0; f < 4; ++f) {
            short8 kf = *(const short8*)&k[((size_t)bh * NN + kt + f * 16 + c) * DKK + quad * 8];
            s[f] = __builtin_amdgcn_mfma_f32_16x16x32_bf16(qf, kf, zero, 0, 0, 0);
        }
        const short* bp = &bsw[(((size_t)h * 64 + t) * 16 + kti) * 1024 + (size_t)lane * 16];
        short8 b0 = *(const short8*)bp;
        short8 b1 = *(const short8*)(bp + 8);
#pragma unroll
        for (int f = 0; f < 4; ++f)
#pragma unroll
            for (int r = 0; r < 4; ++r) {
                int jj = f * 4 + r;
                unsigned short uu = (unsigned short)((jj < 8) ? b0[jj] : b1[jj - 8]);
                s[f][r] += bf2f(uu);
            }
#pragma unroll
        for (int r = 0; r < 4; ++r) {
            float mt2 = fmaxf(fmaxf(s[0][r], s[1][r]), fmaxf(s[2][r], s[3][r]));
#pragma unroll
            for (int off = 1; off < 16; off <<= 1) mt2 = fmaxf(mt2, __shfl_xor(mt2, off));
            float mn = fmaxf(m_i[r], mt2);
            float alpha = __expf(m_i[r] - mn);
            m_i[r] = mn;
            float rs = 0.f;
#pragma unroll
            for (int f = 0; f < 4; ++f) {
                float pr = __expf(s[f][r] - mn);
                s[f][r] = pr;
                rs += pr;
            }
#pragma unroll
            for (int off = 1; off < 16; off <<= 1) rs += __shfl_xor(rs, off);
            l_i[r] = l_i[r] * alpha + rs;
            Oa0[r] *= alpha;
            Oa1[r] *= alpha;
        }
#pragma unroll
        for (int f = 0; f < 4; ++f)
#pragma unroll
            for (int r = 0; r < 4; ++r)
                P[quad * 4 + r][f * 16 + c] = (short)f2bf(s[f][r]);
#pragma unroll
        for (int kc = 0; kc < 2; ++kc) {
            short8 pf = *(const short8*)&P[c][kc * 32 + quad * 8];
            short8 vf0 = *(const short8*)&vt[((size_t)bh * DKK + 0  + c) * NN + kt + kc * 32 + quad * 8];
            short8 vf1 = *(const short8*)&vt[((size_t)bh * DKK + 16 + c) * NN + kt + kc * 32 + quad * 8];
            Oa0 = __builtin_amdgcn_mfma_f32_16x16x32_bf16(pf, vf0, Oa0, 0, 0, 0);
            Oa1 = __builtin_amdgcn_mfma_f32_16x16x32_bf16(pf, vf1, Oa1, 0, 0, 0);
        }
    }
    if (c == 0)
#pragma unroll
        for (int r = 0; r < 4; ++r) {
            Ml[wave][quad * 4 + r][0] = m_i[r];
            Ml[wave][quad * 4 + r][1] = l_i[r];
        }
#pragma unroll
    for (int r = 0; r < 4; ++r) {
        Om[wave][quad * 4 + r][c]      = Oa0[r];
        Om[wave][quad * 4 + r][16 + c] = Oa1[r];
    }
    __syncthreads();
    int row = tid >> 4;
    float mg = fmaxf(fmaxf(Ml[0][row][0], Ml[1][row][0]),
                     fmaxf(Ml[2][row][0], Ml[3][row][0]));
    float sc[4], lg = 0.f;
#pragma unroll
    for (int w = 0; w < 4; ++w) {
        sc[w] = __expf(Ml[w][row][0] - mg);
        lg += Ml[w][row][1] * sc[w];
    }
    float invl = 1.0f / lg;
    int col0 = (tid & 15) * 2;
    float o0 = 0.f, o1 = 0.f;
#pragma unroll
    for (int w = 0; w < 4; ++w) {
        o0 += Om[w][row][col0] * sc[w];
        o1 += Om[w][row][col0 + 1] * sc[w];
    }
    ushort2 pk;
    pk.x = f2bf(o0 * invl);
    pk.y = f2bf(o1 * invl);
    *(ushort2*)&o[((size_t)b * NN + q0 + row) * DD + h * DKK + col0] = pk;
}

// ---------------------------------------------------------------------------
// Fused post-attention (+ optional next-layer QKV), 512 threads = 8 waves.
// Wave covers 32 cols (2 col-frags). Block = 16 rows. Grid 256.
// Wa+res+LN1 -> W1+ReLU (LDS) -> W2+res+LN2 [-> QKV of next layer from LDS].
// ---------------------------------------------------------------------------
template <int QKV>
__global__ __launch_bounds__(512) void post_kernel(
    const short* __restrict__ obb,
    const short* __restrict__ Wta, const short* __restrict__ Wt1,
    const short* __restrict__ Wt2,
    const float* __restrict__ ba, const float* __restrict__ b1,
    const float* __restrict__ b2,
    const float* __restrict__ g1, const float* __restrict__ lb1,
    const float* __restrict__ g2, const float* __restrict__ lb2,
    float* __restrict__ h, short* __restrict__ hb,
    const short* __restrict__ Wtqn, const short* __restrict__ Wtkn,
    const short* __restrict__ Wtvn,
    const float* __restrict__ bqn, const float* __restrict__ bkn,
    const float* __restrict__ bvn,
    short* __restrict__ qo, short* __restrict__ ko, short* __restrict__ vo)
{
    int tid = threadIdx.x, wave = tid >> 6, lane = tid & 63;
    int quad = lane >> 4, c = lane & 15;
    int m0 = blockIdx.x * 16;
    int nb = wave * 32;                 // wave's 32-col base

    __shared__ short t_in[16][264];
    __shared__ short t1s[16][264];
    __shared__ float shs[8][16][2];
    const f32x4 zero = {0.f, 0.f, 0.f, 0.f};

    // ---- Wa GEMM (2 col-frags per wave) ----
    f32x4 acc[2] = {zero, zero};
    {
        const short* Ap = &obb[(size_t)(m0 + c) * DD];
#pragma unroll
        for (int ks = 0; ks < 8; ++ks) {
            short8 af = *(const short8*)&Ap[ks * 32 + quad * 8];
#pragma unroll
            for (int f = 0; f < 2; ++f) {
                short8 bf = *(const short8*)&Wta[(size_t)(nb + f * 16 + c) * DD + ks * 32 + quad * 8];
                acc[f] = __builtin_amdgcn_mfma_f32_16x16x32_bf16(af, bf, acc[f], 0, 0, 0);
            }
        }
    }
    // ---- residual + LN1 ----
    float val[2][4];
    float ps[4] = {0.f,0.f,0.f,0.f}, ps2[4] = {0.f,0.f,0.f,0.f};
#pragma unroll
    for (int f = 0; f < 2; ++f) {
        int col = nb + f * 16 + c;
        float bv = ba[col];
#pragma unroll
        for (int r = 0; r < 4; ++r) {
            float v = h[(size_t)(m0 + quad * 4 + r) * DD + col] + acc[f][r] + bv;
            val[f][r] = v;
            ps[r] += v;
            ps2[r] += v * v;
        }
    }
#pragma unroll
    for (int r = 0; r < 4; ++r)
#pragma unroll
        for (int off = 1; off < 16; off <<= 1) {
            ps[r]  += __shfl_xor(ps[r], off);
            ps2[r] += __shfl_xor(ps2[r], off);
        }
    if (c == 0)
#pragma unroll
        for (int r = 0; r < 4; ++r) {
            shs[wave][quad * 4 + r][0] = ps[r];
            shs[wave][quad * 4 + r][1] = ps2[r];
        }
    __syncthreads();
    float res[2][4];
#pragma unroll
    for (int r = 0; r < 4; ++r) {
        int rr = quad * 4 + r;
        float ts = 0.f, t2 = 0.f;
#pragma unroll
        for (int w = 0; w < 8; ++w) { ts += shs[w][rr][0]; t2 += shs[w][rr][1]; }
        float mu = ts * (1.0f / DD);
        float rv = rsqrtf(t2 * (1.0f / DD) - mu * mu + EPSF);
#pragma unroll
        for (int f = 0; f < 2; ++f) {
            int col = nb + f * 16 + c;
            float nv = (val[f][r] - mu) * rv * g1[col] + lb1[col];
            res[f][r] = nv;
            short bfv = (short)f2bf(nv);
            hb[(size_t)(m0 + rr) * DD + col] = bfv;
            t_in[rr][col] = bfv;
        }
    }
    __syncthreads();
    // ---- W1 + ReLU -> t1s ----
#pragma unroll
    for (int f = 0; f < 2; ++f) {
        int n0 = nb + f * 16;
        f32x4 a1 = zero;
#pragma unroll
        for (int ks = 0; ks < 8; ++ks) {
            short8 af = *(const short8*)&t_in[c][ks * 32 + quad * 8];
            short8 bf = *(const short8*)&Wt1[(size_t)(n0 + c) * DD + ks * 32 + quad * 8];
            a1 = __builtin_amdgcn_mfma_f32_16x16x32_bf16(af, bf, a1, 0, 0, 0);
        }
        float bv = b1[n0 + c];
#pragma unroll
        for (int r = 0; r < 4; ++r)
            t1s[quad * 4 + r][n0 + c] = (short)f2bf(fmaxf(a1[r] + bv, 0.f));
    }
    __syncthreads();
    // ---- W2 GEMM ----
    f32x4 acc2[2] = {zero, zero};
#pragma unroll
    for (int ks = 0; ks < 8; ++ks) {
        short8 af = *(const short8*)&t1s[c][ks * 32 + quad * 8];
#pragma unroll
        for (int f = 0; f < 2; ++f) {
            short8 bf = *(const short8*)&Wt2[(size_t)(nb + f * 16 + c) * DD + ks * 32 + quad * 8];
            acc2[f] = __builtin_amdgcn_mfma_f32_16x16x32_bf16(af, bf, acc2[f], 0, 0, 0);
        }
    }
    // ---- residual + LN2 ----
    float ps_2[4] = {0.f,0.f,0.f,0.f}, ps2_2[4] = {0.f,0.f,0.f,0.f};
#pragma unroll
    for (int f = 0; f < 2; ++f) {
        int col = nb + f * 16 + c;
        float bv = b2[col];
#pragma unroll
        for (int r = 0; r < 4; ++r) {
            float v = res[f][r] + acc2[f][r] + bv;
            val[f][r] = v;
            ps_2[r] += v;
            ps2_2[r] += v * v;
        }
    }
#pragma unroll
    for (int r = 0; r < 4; ++r)
#pragma unroll
        for (int off = 1; off < 16; off <<= 1) {
            ps_2[r]  += __shfl_xor(ps_2[r], off);
            ps2_2[r] += __shfl_xor(ps2_2[r], off);
        }
    __syncthreads();          // LN1 shs reads complete before overwrite
    if (c == 0)
#pragma unroll
        for (int r = 0; r < 4; ++r) {
            shs[wave][quad * 4 + r][0] = ps_2[r];
            shs[wave][quad * 4 + r][1] = ps2_2[r];
        }
    __syncthreads();
#pragma unroll
    for (int r = 0; r < 4; ++r) {
        int rr = quad * 4 + r;
        float ts = 0.f, t2 = 0.f;
#pragma unroll
        for (int w = 0; w < 8; ++w) { ts += shs[w][rr][0]; t2 += shs[w][rr][1]; }
        float mu = ts * (1.0f / DD);
        float rv = rsqrtf(t2 * (1.0f / DD) - mu * mu + EPSF);
#pragma unroll
        for (int f = 0; f < 2; ++f) {
            int col = nb + f * 16 + c;
            float nv = (val[f][r] - mu) * rv * g2[col] + lb2[col];
            h[(size_t)(m0 + rr) * DD + col] = nv;
            short bfv = (short)f2bf(nv);
            hb[(size_t)(m0 + rr) * DD + col] = bfv;
            t_in[rr][col] = bfv;           // stage for next-layer QKV
        }
    }
    if (QKV == 0) return;
    __syncthreads();
    // ---- next-layer QKV from t_in ----
    {
        int b = m0 >> 10;
        int tok0 = (m0 & (NN - 1)) + quad * 4;
        const short* Wz[3]  = {Wtqn, Wtkn, Wtvn};
        const float* bz[3]  = {bqn, bkn, bvn};
        const float scale = 0.17677669529663687f;
#pragma unroll
        for (int z = 0; z < 3; ++z) {
#pragma unroll
            for (int f = 0; f < 2; ++f) {
                int n0 = nb + f * 16;
                f32x4 aq = zero;
#pragma unroll
                for (int ks = 0; ks < 8; ++ks) {
                    short8 af = *(const short8*)&t_in[c][ks * 32 + quad * 8];
                    short8 bf = *(const short8*)&Wz[z][(size_t)(n0 + c) * DD + ks * 32 + quad * 8];
                    aq = __builtin_amdgcn_mfma_f32_16x16x32_bf16(af, bf, aq, 0, 0, 0);
                }
                int col = n0 + c;
                int head = col >> 5, dk = col & 31;
                int bh = b * 8 + head;
                float bv2 = bz[z][col];
                if (z == 2) {
                    ushort4 pk;
                    pk.x = f2bf(aq[0] + bv2); pk.y = f2bf(aq[1] + bv2);
                    pk.z = f2bf(aq[2] + bv2); pk.w = f2bf(aq[3] + bv2);
                    *(ushort4*)&vo[((size_t)bh * DKK + dk) * NN + tok0] = pk;
                } else {
                    short* out = (z == 0) ? qo : ko;
                    float sc = (z == 0) ? scale : 1.0f;
#pragma unroll
                    for (int r = 0; r < 4; ++r)
                        out[((size_t)bh * NN + tok0 + r) * DKK + dk] =
                            (short)f2bf((aq[r] + bv2) * sc);
                }
            }
        }
    }
}

// ---------------------------------------------------------------------------
extern "C" void kernel_launch(void* const* d_in, const int* in_sizes, int n_in,
                              void* d_out, int out_size, void* d_ws, size_t ws_size,
                              hipStream_t stream)
{
    const float* x       = (const float*)d_in[0];
    const int*   deg_in  = (const int*)d_in[1];
    const int*   deg_out = (const int*)d_in[2];
    const int*   sp      = (const int*)d_in[3];
    const float* svd     = (const float*)d_in[4];
    const float* in_emb  = (const float*)d_in[5];
    const float* out_emb = (const float*)d_in[6];
    const float* spemb   = (const float*)d_in[7];
    const float* Wsvd    = (const float*)d_in[8];
    const float* bsvd    = (const float*)d_in[9];
    const float* Wq = (const float*)d_in[10];
    const float* Wk = (const float*)d_in[11];
    const float* Wv = (const float*)d_in[12];
    const float* Wa = (const float*)d_in[13];
    const float* W1 = (const float*)d_in[14];
    const float* W2 = (const float*)d_in[15];
    const float* bq = (const float*)d_in[16];
    const float* bk = (const float*)d_in[17];
    const float* bv = (const float*)d_in[18];
    const float* ba = (const float*)d_in[19];
    const float* b1 = (const float*)d_in[20];
    const float* b2 = (const float*)d_in[21];
    const float* ln1b = (const float*)d_in[22];
    const float* ln2b = (const float*)d_in[23];
    const float* ln1g = (const float*)d_in[24];
    const float* ln2g = (const float*)d_in[25];

    float* h = (float*)d_out;
    char*  ws = (char*)d_ws;
    short* bias = (short*)ws;                         // 16 MB swizzled bf16 bias
    short* qb   = (short*)(ws + ((size_t)16 << 20));  // 2 MB
    short* kb   = (short*)(ws + ((size_t)18 << 20));  // 2 MB
    short* vtb  = (short*)(ws + ((size_t)20 << 20));  // 2 MB
    short* obb  = (short*)(ws + ((size_t)22 << 20));  // 2 MB
    short* hb   = (short*)(ws + ((size_t)26 << 20));  // 2 MB bf16 shadow of h
    short* Wt   = (short*)(ws + ((size_t)28 << 20));  // 3 MB transposed weights

    init_kernel<<<MM, 256, 0, stream>>>(x, deg_in, deg_out, svd, in_emb,
        out_emb, Wsvd, bsvd, Wq, Wk, Wv, Wa, W1, W2, sp, spemb, h, hb, Wt, bias);

    const size_t WSZ = (size_t)DD * DD;
    // layer-0 QKV
    gemm_qkv_kernel<<<dim3(MM / 16, 4, 3), 256, 0, stream>>>(
        hb, Wt + 0 * WSZ, Wt + 4 * WSZ, Wt + 8 * WSZ, bq, bk, bv, qb, kb, vtb);

    for (int l = 0; l < LL; ++l) {
        const size_t bo = (size_t)l * DD;
        const short* Wta = Wt + (3 * 4 + l) * WSZ;
        const short* Wt1 = Wt + (4 * 4 + l) * WSZ;
        const short* Wt2 = Wt + (5 * 4 + l) * WSZ;

        attn_kernel<<<dim3(NN / 16, BB * HH), 256, 0, stream>>>(
            qb, kb, vtb, bias, obb);

        if (l < LL - 1) {
            const size_t bo_n = (size_t)(l + 1) * DD;
            post_kernel<1><<<MM / 16, 512, 0, stream>>>(
                obb, Wta, Wt1, Wt2, ba + bo, b1 + bo, b2 + bo,
                ln1g + bo, ln1b + bo, ln2g + bo, ln2b + bo, h, hb,
                Wt + (0 * 4 + l + 1) * WSZ, Wt + (1 * 4 + l + 1) * WSZ,
                Wt + (2 * 4 + l + 1) * WSZ,
                bq + bo_n, bk + bo_n, bv + bo_n, qb, kb, vtb);
        } else {
            post_kernel<0><<<MM / 16, 512, 0, stream>>>(
                obb, Wta, Wt1, Wt2, ba + bo, b1 + bo, b2 + bo,
                ln1g + bo, ln1b + bo, ln2g + bo, ln2b + bo, h, hb,
                nullptr, nullptr, nullptr, nullptr, nullptr, nullptr,
                nullptr, nullptr, nullptr);
        }
    }
}

// Round 11
// 352.176 us; speedup vs baseline: 3.9582x; 1.0489x over previous
//
#include <hip/hip_runtime.h>
#include <hip/hip_bf16.h>
#include <math.h>

#define NN 1024
#define BB 4
#define HH 8
#define DD 256
#define LL 4
#define DKK 32
#define MM 4096
#define EPSF 1e-6f

typedef __attribute__((ext_vector_type(8))) short short8;
typedef __attribute__((ext_vector_type(4))) float f32x4;

__device__ __forceinline__ unsigned short f2bf(float f) {
    __hip_bfloat16 h = __float2bfloat16(f);
    return *(unsigned short*)&h;
}
__device__ __forceinline__ float bf2f(unsigned short u) {
    unsigned v = ((unsigned)u) << 16;
    return __builtin_bit_cast(float, v);
}

// ---------------------------------------------------------------------------
// init: every block does one prologue row; blocks 0..383 also transpose a
// weight tile; blocks 384..639 also swizzle a bias slab.
// ---------------------------------------------------------------------------
__global__ __launch_bounds__(256) void init_kernel(
    const float* __restrict__ x, const int* __restrict__ deg_in,
    const int* __restrict__ deg_out, const float* __restrict__ svd,
    const float* __restrict__ in_emb, const float* __restrict__ out_emb,
    const float* __restrict__ Wsvd, const float* __restrict__ bsvd,
    const float* __restrict__ Wq, const float* __restrict__ Wk,
    const float* __restrict__ Wv, const float* __restrict__ Wa,
    const float* __restrict__ W1, const float* __restrict__ W2,
    const int* __restrict__ sp, const float* __restrict__ spemb,
    float* __restrict__ h, short* __restrict__ hb,
    short* __restrict__ Wt, short* __restrict__ bsw)
{
    int blk = blockIdx.x;
    int tid = threadIdx.x;
    {
        int n = blk & (NN - 1);
        int di = deg_in[n], dou = deg_out[n];
        float acc = x[(size_t)blk * DD + tid] + in_emb[(size_t)di * DD + tid]
                  + out_emb[(size_t)dou * DD + tid] + bsvd[tid];
        const float* sv = &svd[n * 32];
#pragma unroll
        for (int j = 0; j < 32; ++j) {
            float v = sv[j];
            v = (j < 16) ? v : -v;
            acc += v * Wsvd[j * DD + tid];
        }
        h[(size_t)blk * DD + tid] = acc;
        hb[(size_t)blk * DD + tid] = (short)f2bf(acc);
    }
    if (blk < 384) {
        __shared__ float t[64][65];
        int z = blk >> 4, tile = blk & 15;
        int name = z >> 2;
        const float* srcs[6] = {Wq, Wk, Wv, Wa, W1, W2};
        const float* W = srcs[name] + (size_t)(z & 3) * DD * DD;
        short* dst = Wt + (size_t)z * DD * DD;
        int r0 = (tile >> 2) * 64, c0 = (tile & 3) * 64;
#pragma unroll
        for (int i = 0; i < 16; ++i) {
            int idx = i * 256 + tid;
            int r = idx >> 6, cc = idx & 63;
            t[r][cc] = W[(size_t)(r0 + r) * DD + c0 + cc];
        }
        __syncthreads();
#pragma unroll
        for (int i = 0; i < 16; ++i) {
            int idx = i * 256 + tid;
            int n = idx >> 6, k = idx & 63;
            dst[(size_t)(c0 + n) * DD + r0 + k] = (short)f2bf(t[k][n]);
        }
    } else if (blk < 640) {
        int tt = (blk - 384) * 256 + tid;       // (q16, kt, lane)
        int ln = tt & 63, kt = (tt >> 6) & 15, q16 = tt >> 10;
        int qd = ln >> 4, cc = ln & 15;
        unsigned buf[8][8];
#pragma unroll
        for (int j = 0; j < 16; ++j) {
            int f = j >> 2, r = j & 3;
            int row = q16 * 16 + qd * 4 + r;
            int col = kt * 64 + f * 16 + cc;
            int pp = sp[row * NN + col];
#pragma unroll
            for (int hh = 0; hh < 8; ++hh) {
                unsigned short u = f2bf(spemb[pp * 8 + hh]);
                if (j & 1) buf[hh][j >> 1] |= ((unsigned)u) << 16;
                else       buf[hh][j >> 1] = u;
            }
        }
#pragma unroll
        for (int hh = 0; hh < 8; ++hh) {
            uint4* dst = (uint4*)&bsw[(((size_t)hh * 64 + q16) * 16 + kt) * 1024 + (size_t)ln * 16];
            dst[0] = make_uint4(buf[hh][0], buf[hh][1], buf[hh][2], buf[hh][3]);
            dst[1] = make_uint4(buf[hh][4], buf[hh][5], buf[hh][6], buf[hh][7]);
        }
    }
}

// ---------------------------------------------------------------------------
// QKV bf16 GEMM (layer 0 only), wave = 16x16 tile. Grid (MM/16, 4, 3).
// ---------------------------------------------------------------------------
__global__ __launch_bounds__(256) void gemm_qkv_kernel(
    const short* __restrict__ A,
    const short* __restrict__ Wtq, const short* __restrict__ Wtk,
    const short* __restrict__ Wtv,
    const float* __restrict__ bq, const float* __restrict__ bk,
    const float* __restrict__ bv,
    short* __restrict__ qo, short* __restrict__ ko, short* __restrict__ vo)
{
    int z = blockIdx.z;
    const short* Wt = (z == 0) ? Wtq : (z == 1) ? Wtk : Wtv;
    const float* bs = (z == 0) ? bq : (z == 1) ? bk : bv;
    int tid = threadIdx.x, wave = tid >> 6, lane = tid & 63;
    int quad = lane >> 4, c = lane & 15;
    int m0 = blockIdx.x * 16;
    int n0 = blockIdx.y * 64 + wave * 16;
    f32x4 acc = {0.f, 0.f, 0.f, 0.f};
    const short* Ap = &A[(size_t)(m0 + c) * DD];
#pragma unroll
    for (int ks = 0; ks < 8; ++ks) {
        short8 af = *(const short8*)&Ap[ks * 32 + quad * 8];
        short8 bf = *(const short8*)&Wt[(size_t)(n0 + c) * DD + ks * 32 + quad * 8];
        acc = __builtin_amdgcn_mfma_f32_16x16x32_bf16(af, bf, acc, 0, 0, 0);
    }
    int b = m0 >> 10;
    int tok0 = (m0 & (NN - 1)) + quad * 4;
    int col = n0 + c;
    int head = col >> 5, dk = col & 31;
    int bh = b * 8 + head;
    float bv2 = bs[col];
    const float scale = 0.17677669529663687f;
    if (z == 2) {
        ushort4 pk;
        pk.x = f2bf(acc[0] + bv2); pk.y = f2bf(acc[1] + bv2);
        pk.z = f2bf(acc[2] + bv2); pk.w = f2bf(acc[3] + bv2);
        *(ushort4*)&vo[((size_t)bh * DKK + dk) * NN + tok0] = pk;
    } else {
        short* out = (z == 0) ? qo : ko;
        float sc = (z == 0) ? scale : 1.0f;
#pragma unroll
        for (int r = 0; r < 4; ++r)
            out[((size_t)bh * NN + tok0 + r) * DKK + dk] =
                (short)f2bf((acc[r] + bv2) * sc);
    }
}

// ---------------------------------------------------------------------------
// Fused layer kernel: attention (wave = head, full K range, online softmax)
// -> Wa+res+LN1 -> W1+ReLU -> W2+res+LN2 [-> next-layer QKV].
// Block = 16 token rows, 512 threads = 8 waves. Grid MM/16 = 256.
// Attention output never leaves LDS.
// ---------------------------------------------------------------------------
template <int QKV>
__global__ __launch_bounds__(512) void layer_kernel(
    const short* __restrict__ q, const short* __restrict__ k,
    const short* __restrict__ vt, const short* __restrict__ bsw,
    const short* __restrict__ Wta, const short* __restrict__ Wt1,
    const short* __restrict__ Wt2,
    const float* __restrict__ ba, const float* __restrict__ b1,
    const float* __restrict__ b2,
    const float* __restrict__ g1, const float* __restrict__ lb1,
    const float* __restrict__ g2, const float* __restrict__ lb2,
    float* __restrict__ h,
    const short* __restrict__ Wtqn, const short* __restrict__ Wtkn,
    const short* __restrict__ Wtvn,
    const float* __restrict__ bqn, const float* __restrict__ bkn,
    const float* __restrict__ bvn,
    short* __restrict__ qo, short* __restrict__ ko, short* __restrict__ vo)
{
    int tid = threadIdx.x, wave = tid >> 6, lane = tid & 63;
    int quad = lane >> 4, c = lane & 15;
    int m0 = blockIdx.x * 16;
    int b = m0 >> 10;
    int q0 = m0 & (NN - 1);           // token offset within batch
    int qt_idx = q0 >> 4;             // q16 tile index 0..63
    int head = wave;                  // one wave per head
    int bh = b * 8 + head;
    int nb = wave * 32;               // post-phase: wave's 32-col base

    __shared__ short Pl[8][16][72];   // 18432 B, per-wave P tiles
    __shared__ short t_in[16][264];   // 8448 B
    __shared__ short t1s[16][264];    // 8448 B
    __shared__ float shs[8][16][2];   // 1024 B
    const f32x4 zero = {0.f, 0.f, 0.f, 0.f};

    // ================= attention phase (wave-private) ======================
    {
        short (*P)[72] = Pl[wave];
        short8 qf = *(const short8*)&q[((size_t)bh * NN + q0 + c) * DKK + quad * 8];
        float m_i[4], l_i[4];
        f32x4 Oa0 = zero, Oa1 = zero;
#pragma unroll
        for (int r = 0; r < 4; ++r) { m_i[r] = -1e30f; l_i[r] = 0.f; }

        for (int kti = 0; kti < 16; ++kti) {
            int kt = kti * 64;
            f32x4 s[4];
#pragma unroll
            for (int f = 0; f < 4; ++f) {
                short8 kf = *(const short8*)&k[((size_t)bh * NN + kt + f * 16 + c) * DKK + quad * 8];
                s[f] = __builtin_amdgcn_mfma_f32_16x16x32_bf16(qf, kf, zero, 0, 0, 0);
            }
            const short* bp = &bsw[(((size_t)head * 64 + qt_idx) * 16 + kti) * 1024 + (size_t)lane * 16];
            short8 b0 = *(const short8*)bp;
            short8 b1v = *(const short8*)(bp + 8);
#pragma unroll
            for (int f = 0; f < 4; ++f)
#pragma unroll
                for (int r = 0; r < 4; ++r) {
                    int jj = f * 4 + r;
                    unsigned short uu = (unsigned short)((jj < 8) ? b0[jj] : b1v[jj - 8]);
                    s[f][r] += bf2f(uu);
                }
#pragma unroll
            for (int r = 0; r < 4; ++r) {
                float mt2 = fmaxf(fmaxf(s[0][r], s[1][r]), fmaxf(s[2][r], s[3][r]));
#pragma unroll
                for (int off = 1; off < 16; off <<= 1) mt2 = fmaxf(mt2, __shfl_xor(mt2, off));
                float mn = fmaxf(m_i[r], mt2);
                float alpha = __expf(m_i[r] - mn);
                m_i[r] = mn;
                float rs = 0.f;
#pragma unroll
                for (int f = 0; f < 4; ++f) {
                    float pr = __expf(s[f][r] - mn);
                    s[f][r] = pr;
                    rs += pr;
                }
#pragma unroll
                for (int off = 1; off < 16; off <<= 1) rs += __shfl_xor(rs, off);
                l_i[r] = l_i[r] * alpha + rs;
                Oa0[r] *= alpha;
                Oa1[r] *= alpha;
            }
#pragma unroll
            for (int f = 0; f < 4; ++f)
#pragma unroll
                for (int r = 0; r < 4; ++r)
                    P[quad * 4 + r][f * 16 + c] = (short)f2bf(s[f][r]);
#pragma unroll
            for (int kc = 0; kc < 2; ++kc) {
                short8 pf = *(const short8*)&P[c][kc * 32 + quad * 8];
                short8 vf0 = *(const short8*)&vt[((size_t)bh * DKK + 0  + c) * NN + kt + kc * 32 + quad * 8];
                short8 vf1 = *(const short8*)&vt[((size_t)bh * DKK + 16 + c) * NN + kt + kc * 32 + quad * 8];
                Oa0 = __builtin_amdgcn_mfma_f32_16x16x32_bf16(pf, vf0, Oa0, 0, 0, 0);
                Oa1 = __builtin_amdgcn_mfma_f32_16x16x32_bf16(pf, vf1, Oa1, 0, 0, 0);
            }
        }
        // epilogue: divide, stage attn output into t_in (cols head*32..+31)
#pragma unroll
        for (int r = 0; r < 4; ++r) {
            float invl = 1.0f / l_i[r];
            int rr = quad * 4 + r;
            t_in[rr][head * 32 + c]      = (short)f2bf(Oa0[r] * invl);
            t_in[rr][head * 32 + 16 + c] = (short)f2bf(Oa1[r] * invl);
        }
    }
    __syncthreads();

    // ================= Wa GEMM (A from t_in) ===============================
    f32x4 acc[2] = {zero, zero};
#pragma unroll
    for (int ks = 0; ks < 8; ++ks) {
        short8 af = *(const short8*)&t_in[c][ks * 32 + quad * 8];
#pragma unroll
        for (int f = 0; f < 2; ++f) {
            short8 bf = *(const short8*)&Wta[(size_t)(nb + f * 16 + c) * DD + ks * 32 + quad * 8];
            acc[f] = __builtin_amdgcn_mfma_f32_16x16x32_bf16(af, bf, acc[f], 0, 0, 0);
        }
    }
    // ---- residual + LN1 ----
    float val[2][4];
    float ps[4] = {0.f,0.f,0.f,0.f}, ps2[4] = {0.f,0.f,0.f,0.f};
#pragma unroll
    for (int f = 0; f < 2; ++f) {
        int col = nb + f * 16 + c;
        float bv = ba[col];
#pragma unroll
        for (int r = 0; r < 4; ++r) {
            float v = h[(size_t)(m0 + quad * 4 + r) * DD + col] + acc[f][r] + bv;
            val[f][r] = v;
            ps[r] += v;
            ps2[r] += v * v;
        }
    }
#pragma unroll
    for (int r = 0; r < 4; ++r)
#pragma unroll
        for (int off = 1; off < 16; off <<= 1) {
            ps[r]  += __shfl_xor(ps[r], off);
            ps2[r] += __shfl_xor(ps2[r], off);
        }
    if (c == 0)
#pragma unroll
        for (int r = 0; r < 4; ++r) {
            shs[wave][quad * 4 + r][0] = ps[r];
            shs[wave][quad * 4 + r][1] = ps2[r];
        }
    __syncthreads();    // also separates Wa t_in reads from LN1 t_in writes
    float res[2][4];
#pragma unroll
    for (int r = 0; r < 4; ++r) {
        int rr = quad * 4 + r;
        float ts = 0.f, t2 = 0.f;
#pragma unroll
        for (int w = 0; w < 8; ++w) { ts += shs[w][rr][0]; t2 += shs[w][rr][1]; }
        float mu = ts * (1.0f / DD);
        float rv = rsqrtf(t2 * (1.0f / DD) - mu * mu + EPSF);
#pragma unroll
        for (int f = 0; f < 2; ++f) {
            int col = nb + f * 16 + c;
            float nv = (val[f][r] - mu) * rv * g1[col] + lb1[col];
            res[f][r] = nv;
            t_in[rr][col] = (short)f2bf(nv);
        }
    }
    __syncthreads();
    // ---- W1 + ReLU -> t1s ----
#pragma unroll
    for (int f = 0; f < 2; ++f) {
        int n0 = nb + f * 16;
        f32x4 a1 = zero;
#pragma unroll
        for (int ks = 0; ks < 8; ++ks) {
            short8 af = *(const short8*)&t_in[c][ks * 32 + quad * 8];
            short8 bf = *(const short8*)&Wt1[(size_t)(n0 + c) * DD + ks * 32 + quad * 8];
            a1 = __builtin_amdgcn_mfma_f32_16x16x32_bf16(af, bf, a1, 0, 0, 0);
        }
        float bv = b1[n0 + c];
#pragma unroll
        for (int r = 0; r < 4; ++r)
            t1s[quad * 4 + r][n0 + c] = (short)f2bf(fmaxf(a1[r] + bv, 0.f));
    }
    __syncthreads();
    // ---- W2 GEMM ----
    f32x4 acc2[2] = {zero, zero};
#pragma unroll
    for (int ks = 0; ks < 8; ++ks) {
        short8 af = *(const short8*)&t1s[c][ks * 32 + quad * 8];
#pragma unroll
        for (int f = 0; f < 2; ++f) {
            short8 bf = *(const short8*)&Wt2[(size_t)(nb + f * 16 + c) * DD + ks * 32 + quad * 8];
            acc2[f] = __builtin_amdgcn_mfma_f32_16x16x32_bf16(af, bf, acc2[f], 0, 0, 0);
        }
    }
    // ---- residual + LN2 ----
    float ps_2[4] = {0.f,0.f,0.f,0.f}, ps2_2[4] = {0.f,0.f,0.f,0.f};
#pragma unroll
    for (int f = 0; f < 2; ++f) {
        int col = nb + f * 16 + c;
        float bv = b2[col];
#pragma unroll
        for (int r = 0; r < 4; ++r) {
            float v = res[f][r] + acc2[f][r] + bv;
            val[f][r] = v;
            ps_2[r] += v;
            ps2_2[r] += v * v;
        }
    }
#pragma unroll
    for (int r = 0; r < 4; ++r)
#pragma unroll
        for (int off = 1; off < 16; off <<= 1) {
            ps_2[r]  += __shfl_xor(ps_2[r], off);
            ps2_2[r] += __shfl_xor(ps2_2[r], off);
        }
    __syncthreads();          // LN1 shs reads complete before overwrite
    if (c == 0)
#pragma unroll
        for (int r = 0; r < 4; ++r) {
            shs[wave][quad * 4 + r][0] = ps_2[r];
            shs[wave][quad * 4 + r][1] = ps2_2[r];
        }
    __syncthreads();
#pragma unroll
    for (int r = 0; r < 4; ++r) {
        int rr = quad * 4 + r;
        float ts = 0.f, t2 = 0.f;
#pragma unroll
        for (int w = 0; w < 8; ++w) { ts += shs[w][rr][0]; t2 += shs[w][rr][1]; }
        float mu = ts * (1.0f / DD);
        float rv = rsqrtf(t2 * (1.0f / DD) - mu * mu + EPSF);
#pragma unroll
        for (int f = 0; f < 2; ++f) {
            int col = nb + f * 16 + c;
            float nv = (val[f][r] - mu) * rv * g2[col] + lb2[col];
            h[(size_t)(m0 + rr) * DD + col] = nv;
            t_in[rr][col] = (short)f2bf(nv);   // stage for next-layer QKV
        }
    }
    if (QKV == 0) return;
    __syncthreads();
    // ================= next-layer QKV from t_in ============================
    {
        int tok0 = q0 + quad * 4;
        const short* Wz[3]  = {Wtqn, Wtkn, Wtvn};
        const float* bz[3]  = {bqn, bkn, bvn};
        const float scale = 0.17677669529663687f;
#pragma unroll
        for (int z = 0; z < 3; ++z) {
#pragma unroll
            for (int f = 0; f < 2; ++f) {
                int n0 = nb + f * 16;
                f32x4 aq = zero;
#pragma unroll
                for (int ks = 0; ks < 8; ++ks) {
                    short8 af = *(const short8*)&t_in[c][ks * 32 + quad * 8];
                    short8 bf = *(const short8*)&Wz[z][(size_t)(n0 + c) * DD + ks * 32 + quad * 8];
                    aq = __builtin_amdgcn_mfma_f32_16x16x32_bf16(af, bf, aq, 0, 0, 0);
                }
                int col = n0 + c;
                int hd = col >> 5, dk = col & 31;
                int bh2 = b * 8 + hd;
                float bv2 = bz[z][col];
                if (z == 2) {
                    ushort4 pk;
                    pk.x = f2bf(aq[0] + bv2); pk.y = f2bf(aq[1] + bv2);
                    pk.z = f2bf(aq[2] + bv2); pk.w = f2bf(aq[3] + bv2);
                    *(ushort4*)&vo[((size_t)bh2 * DKK + dk) * NN + tok0] = pk;
                } else {
                    short* out = (z == 0) ? qo : ko;
                    float sc = (z == 0) ? scale : 1.0f;
#pragma unroll
                    for (int r = 0; r < 4; ++r)
                        out[((size_t)bh2 * NN + tok0 + r) * DKK + dk] =
                            (short)f2bf((aq[r] + bv2) * sc);
                }
            }
        }
    }
}

// ---------------------------------------------------------------------------
extern "C" void kernel_launch(void* const* d_in, const int* in_sizes, int n_in,
                              void* d_out, int out_size, void* d_ws, size_t ws_size,
                              hipStream_t stream)
{
    const float* x       = (const float*)d_in[0];
    const int*   deg_in  = (const int*)d_in[1];
    const int*   deg_out = (const int*)d_in[2];
    const int*   sp      = (const int*)d_in[3];
    const float* svd     = (const float*)d_in[4];
    const float* in_emb  = (const float*)d_in[5];
    const float* out_emb = (const float*)d_in[6];
    const float* spemb   = (const float*)d_in[7];
    const float* Wsvd    = (const float*)d_in[8];
    const float* bsvd    = (const float*)d_in[9];
    const float* Wq = (const float*)d_in[10];
    const float* Wk = (const float*)d_in[11];
    const float* Wv = (const float*)d_in[12];
    const float* Wa = (const float*)d_in[13];
    const float* W1 = (const float*)d_in[14];
    const float* W2 = (const float*)d_in[15];
    const float* bq = (const float*)d_in[16];
    const float* bk = (const float*)d_in[17];
    const float* bv = (const float*)d_in[18];
    const float* ba = (const float*)d_in[19];
    const float* b1 = (const float*)d_in[20];
    const float* b2 = (const float*)d_in[21];
    const float* ln1b = (const float*)d_in[22];
    const float* ln2b = (const float*)d_in[23];
    const float* ln1g = (const float*)d_in[24];
    const float* ln2g = (const float*)d_in[25];

    float* h = (float*)d_out;
    char*  ws = (char*)d_ws;
    short* bias = (short*)ws;                         // 16 MB swizzled bf16 bias
    short* qb   = (short*)(ws + ((size_t)16 << 20));  // 2 MB
    short* kb   = (short*)(ws + ((size_t)18 << 20));  // 2 MB
    short* vtb  = (short*)(ws + ((size_t)20 << 20));  // 2 MB
    short* hb   = (short*)(ws + ((size_t)26 << 20));  // 2 MB bf16 shadow of h
    short* Wt   = (short*)(ws + ((size_t)28 << 20));  // 3 MB transposed weights

    init_kernel<<<MM, 256, 0, stream>>>(x, deg_in, deg_out, svd, in_emb,
        out_emb, Wsvd, bsvd, Wq, Wk, Wv, Wa, W1, W2, sp, spemb, h, hb, Wt, bias);

    const size_t WSZ = (size_t)DD * DD;
    // layer-0 QKV
    gemm_qkv_kernel<<<dim3(MM / 16, 4, 3), 256, 0, stream>>>(
        hb, Wt + 0 * WSZ, Wt + 4 * WSZ, Wt + 8 * WSZ, bq, bk, bv, qb, kb, vtb);

    for (int l = 0; l < LL; ++l) {
        const size_t bo = (size_t)l * DD;
        const short* Wta = Wt + (3 * 4 + l) * WSZ;
        const short* Wt1 = Wt + (4 * 4 + l) * WSZ;
        const short* Wt2 = Wt + (5 * 4 + l) * WSZ;

        if (l < LL - 1) {
            const size_t bo_n = (size_t)(l + 1) * DD;
            layer_kernel<1><<<MM / 16, 512, 0, stream>>>(
                qb, kb, vtb, bias, Wta, Wt1, Wt2,
                ba + bo, b1 + bo, b2 + bo,
                ln1g + bo, ln1b + bo, ln2g + bo, ln2b + bo, h,
                Wt + (0 * 4 + l + 1) * WSZ, Wt + (1 * 4 + l + 1) * WSZ,
                Wt + (2 * 4 + l + 1) * WSZ,
                bq + bo_n, bk + bo_n, bv + bo_n, qb, kb, vtb);
        } else {
            layer_kernel<0><<<MM / 16, 512, 0, stream>>>(
                qb, kb, vtb, bias, Wta, Wt1, Wt2,
                ba + bo, b1 + bo, b2 + bo,
                ln1g + bo, ln1b + bo, ln2g + bo, ln2b + bo, h,
                nullptr, nullptr, nullptr, nullptr, nullptr, nullptr,
                nullptr, nullptr, nullptr);
        }
    }
}